// Round 2
// baseline (1636.303 us; speedup 1.0000x reference)
//
#include <hip/hip_runtime.h>
#include <hip/hip_bf16.h>

#define F_BIAS 1
#define F_RELU 2
#define F_RES  4

// dst[k*dstStride + colOff + j] = src[j*K + k]   (src: [J rows, K cols] fp32)
__global__ void transpose_w(float* __restrict__ dst, const float* __restrict__ src,
                            int J, int K, int dstStride, int colOff){
  int idx = blockIdx.x*256 + threadIdx.x;
  if (idx >= J*K) return;
  int j = idx / K, k = idx - j*K;
  dst[(size_t)k*dstStride + colOff + j] = src[idx];
}

// Row LayerNorm: one block per row, 256 threads, rowLen in {256, 512}
__global__ __launch_bounds__(256) void ln_kernel(float* __restrict__ dst,
    const float* __restrict__ src, const float* __restrict__ w,
    const float* __restrict__ bvec, int rowLen){
  int row = blockIdx.x, tid = threadIdx.x;
  const float* s = src + (size_t)row*rowLen;
  float x0 = s[tid];
  float x1 = (rowLen > 256) ? s[tid+256] : 0.0f;
  float sum = x0 + x1, sq = x0*x0 + x1*x1;
  #pragma unroll
  for (int off=32; off; off>>=1){
    sum += __shfl_down(sum, off, 64);
    sq  += __shfl_down(sq , off, 64);
  }
  __shared__ float sbs[4], sbq[4];
  int wid = tid>>6, lane = tid&63;
  if (lane==0){ sbs[wid]=sum; sbq[wid]=sq; }
  __syncthreads();
  if (tid==0){
    float a=0, b2=0;
    for (int i=0;i<4;i++){ a+=sbs[i]; b2+=sbq[i]; }
    sbs[0]=a; sbq[0]=b2;
  }
  __syncthreads();
  float inv  = 1.0f/(float)rowLen;
  float mean = sbs[0]*inv;
  float var  = sbq[0]*inv - mean*mean;
  float rstd = rsqrtf(var + 1e-6f);
  float* d = dst + (size_t)row*rowLen;
  d[tid] = (x0-mean)*rstd*w[tid] + bvec[tid];
  if (rowLen > 256)
    d[tid+256] = (x1-mean)*rstd*w[tid+256] + bvec[tid+256];
}

// C[M,N] = A[M,K] @ Bt[K,N] (+bias)(relu)(+resid). Batched via grid.z.
// M%64==0, N%64==0, K%16==0.
__global__ __launch_bounds__(256) void gemm_k(
    const float* __restrict__ A, const float* __restrict__ Bt,
    float* __restrict__ outC,
    const float* __restrict__ bias, const float* __restrict__ resid,
    int M, int N, int K, int flags,
    long long strideA, long long strideB, long long strideO, long long strideR){
  int bz = blockIdx.z;
  A  += (size_t)bz*strideA;
  Bt += (size_t)bz*strideB;
  __shared__ float As[16][68];
  __shared__ float Bs[16][68];
  int tid = threadIdx.x;
  int m0 = blockIdx.x*64, n0 = blockIdx.y*64;
  int tx = tid & 15, ty = tid >> 4;
  int lr = tid & 63, lk = tid >> 6;
  float acc[4][4] = {{0.0f}};
  for (int k0 = 0; k0 < K; k0 += 16){
    const float* ap = A + (size_t)(m0+lr)*K + k0 + lk*4;
    float4 av = *(const float4*)ap;
    As[lk*4+0][lr] = av.x; As[lk*4+1][lr] = av.y;
    As[lk*4+2][lr] = av.z; As[lk*4+3][lr] = av.w;
    #pragma unroll
    for (int q=0;q<4;q++)
      Bs[lk*4+q][lr] = Bt[(size_t)(k0+lk*4+q)*N + n0 + lr];
    __syncthreads();
    #pragma unroll
    for (int k=0;k<16;k++){
      float a0=As[k][ty*4+0], a1=As[k][ty*4+1], a2=As[k][ty*4+2], a3=As[k][ty*4+3];
      float b0=Bs[k][tx*4+0], b1=Bs[k][tx*4+1], b2=Bs[k][tx*4+2], b3=Bs[k][tx*4+3];
      acc[0][0]+=a0*b0; acc[0][1]+=a0*b1; acc[0][2]+=a0*b2; acc[0][3]+=a0*b3;
      acc[1][0]+=a1*b0; acc[1][1]+=a1*b1; acc[1][2]+=a1*b2; acc[1][3]+=a1*b3;
      acc[2][0]+=a2*b0; acc[2][1]+=a2*b1; acc[2][2]+=a2*b2; acc[2][3]+=a2*b3;
      acc[3][0]+=a3*b0; acc[3][1]+=a3*b1; acc[3][2]+=a3*b2; acc[3][3]+=a3*b3;
    }
    __syncthreads();
  }
  #pragma unroll
  for (int i=0;i<4;i++){
    int r = m0 + ty*4 + i;
    #pragma unroll
    for (int j=0;j<4;j++){
      int c = n0 + tx*4 + j;
      float v = acc[i][j];
      if (flags & F_BIAS) v += bias[c];
      if (flags & F_RELU) v = fmaxf(v, 0.0f);
      if (flags & F_RES)
        v += resid[(size_t)bz*strideR + (size_t)r*N + c];
      outC[(size_t)bz*strideO + (size_t)r*N + c] = v;
    }
  }
}

// Temporal causal attention. qkv layout: row = b*512+t (stride 768),
// cols: [0:256)=q, [256:512)=k, [512:768)=v, each col = h*32+d.
// One block per (t,h,b). Writes o[b,t,h*32+d].
__global__ __launch_bounds__(256) void temporal_attn(
    const float* __restrict__ qkv, float* __restrict__ o){
  int t = blockIdx.x, h = blockIdx.y, b = blockIdx.z;
  int tid = threadIdx.x;
  __shared__ float qsh[32];
  __shared__ float p[512];
  __shared__ float rbuf[4];
  __shared__ float part[8][33];
  const float* base = qkv + (size_t)b*512*768;
  if (tid < 32) qsh[tid] = base[(size_t)t*768 + h*32 + tid];
  __syncthreads();
  float sc[2];
  #pragma unroll
  for (int i=0;i<2;i++){
    int s = tid + i*256;
    const float* kr = base + (size_t)s*768 + 256 + h*32;
    float a = 0.0f;
    #pragma unroll
    for (int d=0; d<32; d++) a += qsh[d]*kr[d];
    sc[i] = (s <= t) ? a*0.17677669529663687f : -3.0e38f;
  }
  int wid = tid>>6, lane = tid&63;
  float m = fmaxf(sc[0], sc[1]);
  #pragma unroll
  for (int off=32; off; off>>=1) m = fmaxf(m, __shfl_down(m, off, 64));
  if (lane==0) rbuf[wid]=m;
  __syncthreads();
  if (tid==0){ float mm=rbuf[0]; for(int i=1;i<4;i++) mm=fmaxf(mm,rbuf[i]); rbuf[0]=mm; }
  __syncthreads();
  float Mx = rbuf[0];
  __syncthreads();
  float e0 = (tid       <= t) ? __expf(sc[0]-Mx) : 0.0f;
  float e1 = (tid + 256 <= t) ? __expf(sc[1]-Mx) : 0.0f;
  float ssum = e0 + e1;
  #pragma unroll
  for (int off=32; off; off>>=1) ssum += __shfl_down(ssum, off, 64);
  if (lane==0) rbuf[wid]=ssum;
  __syncthreads();
  if (tid==0){ float s2=0; for(int i=0;i<4;i++) s2+=rbuf[i]; rbuf[0]=s2; }
  __syncthreads();
  float invS = 1.0f/rbuf[0];
  p[tid] = e0*invS; p[tid+256] = e1*invS;
  __syncthreads();
  int d = tid & 31, g = tid >> 5;
  const float* vb = base + 512 + h*32 + d;
  float a = 0.0f;
  for (int s = g*64; s < (g+1)*64; ++s) a += p[s] * vb[(size_t)s*768];
  part[g][d] = a;
  __syncthreads();
  if (tid < 32){
    float r = 0.0f;
    #pragma unroll
    for (int gg=0; gg<8; gg++) r += part[gg][tid];
    o[((size_t)(b*512+t))*256 + h*32 + tid] = r;
  }
}

// Spatial attention. qk layout: row = b*256+c (stride 1024),
// cols [0:512)=qs (h*64+d), [512:1024)=ks. One block per (c,b); thread = e.
// sw[b,c,e] = mean_h softmax_e( qs[b,c,h,:]·ks[b,e,h,:] / 8 )
// Writes fp32 sw to out1 and fp32 swT[b][e][c] for the fusion GEMM.
__global__ __launch_bounds__(256) void spatial_attn(
    const float* __restrict__ qk, float* __restrict__ swT,
    float* __restrict__ swOut){
  int c = blockIdx.x, b = blockIdx.y, e = threadIdx.x;
  __shared__ float qsh[64];
  __shared__ float rbuf[4];
  const float* qrow = qk + ((size_t)(b*256+c))*1024;
  const float* krow = qk + ((size_t)(b*256+e))*1024 + 512;
  int wid = e>>6, lane = e&63;
  float acc = 0.0f;
  for (int h=0; h<8; ++h){
    __syncthreads();
    if (e < 64) qsh[e] = qrow[h*64 + e];
    __syncthreads();
    const float* kp = krow + h*64;
    float s = 0.0f;
    #pragma unroll
    for (int d=0; d<64; d++) s += qsh[d]*kp[d];
    s *= 0.125f;
    float m = s;
    #pragma unroll
    for (int off=32; off; off>>=1) m = fmaxf(m, __shfl_down(m, off, 64));
    if (lane==0) rbuf[wid]=m;
    __syncthreads();
    if (e==0){ float mm=rbuf[0]; for(int i=1;i<4;i++) mm=fmaxf(mm,rbuf[i]); rbuf[0]=mm; }
    __syncthreads();
    float Mx = rbuf[0];
    __syncthreads();
    float ex = __expf(s-Mx);
    float ss = ex;
    #pragma unroll
    for (int off=32; off; off>>=1) ss += __shfl_down(ss, off, 64);
    if (lane==0) rbuf[wid]=ss;
    __syncthreads();
    if (e==0){ float s2=0; for(int i=0;i<4;i++) s2+=rbuf[i]; rbuf[0]=s2; }
    __syncthreads();
    acc += ex / rbuf[0] * 0.125f;
  }
  swT[((size_t)(b*256) + e)*256 + c] = acc;
  swOut[((size_t)(b*256) + c)*256 + e] = acc;
}

extern "C" void kernel_launch(void* const* d_in, const int* in_sizes, int n_in,
                              void* d_out, int out_size, void* d_ws, size_t ws_size,
                              hipStream_t stream){
  (void)in_sizes; (void)n_in; (void)out_size; (void)ws_size;
  const float* x_T  = (const float*)d_in[0];
  const float* x_S  = (const float*)d_in[1];
  const float* Wq_t = (const float*)d_in[2];
  const float* Wk_t = (const float*)d_in[3];
  const float* Wv_t = (const float*)d_in[4];
  const float* Wo   = (const float*)d_in[5];
  const float* Wq_s = (const float*)d_in[6];
  const float* Wk_s = (const float*)d_in[7];
  const float* f1w1 = (const float*)d_in[8];
  const float* f1b1 = (const float*)d_in[9];
  const float* f1w2 = (const float*)d_in[10];
  const float* f1b2 = (const float*)d_in[11];
  const float* f2w1 = (const float*)d_in[12];
  const float* f2b1 = (const float*)d_in[13];
  const float* f2w2 = (const float*)d_in[14];
  const float* f2b2 = (const float*)d_in[15];
  const float* tl1w = (const float*)d_in[16];
  const float* tl1b = (const float*)d_in[17];
  const float* tl2w = (const float*)d_in[18];
  const float* tl2b = (const float*)d_in[19];
  const float* sl1w = (const float*)d_in[20];
  const float* sl1b = (const float*)d_in[21];
  const float* flw  = (const float*)d_in[22];
  const float* flb  = (const float*)d_in[23];

  float* ws = (float*)d_ws;
  size_t off = 0;
  float* WtQKV = ws + off; off += 256*768;
  float* WtWO  = ws + off; off += 256*256;
  float* WtF1A = ws + off; off += 256*1024;
  float* WtF1B = ws + off; off += 1024*256;
  float* WtS   = ws + off; off += 512*1024;
  float* WtF2A = ws + off; off += 256*1024;
  float* WtF2B = ws + off; off += 1024*256;
  float* bufH  = ws + off; off += (size_t)8192*256;
  float* bufBig= ws + off; off += (size_t)8192*1024;
  float* bufO  = ws + off; off += (size_t)8192*256;
  float* bufX  = ws + off; off += (size_t)8192*256;
  float* bufTO = ws + off; off += (size_t)8192*256;
  float* bufX2 = ws + off; off += (size_t)8192*256;
  float* swT   = ws + off; off += (size_t)16*256*256;

  float* out0 = (float*)d_out;                      // [B,T,C]
  float* out1 = out0 + (size_t)16*512*256;          // spatial_weights [B,C,C]

  // ---- weight transposes (fp32 [J,K] -> fp32 [K x N]) ----
  transpose_w<<<256 ,256,0,stream>>>(WtQKV, Wq_t, 256 ,256 , 768 , 0  );
  transpose_w<<<256 ,256,0,stream>>>(WtQKV, Wk_t, 256 ,256 , 768 , 256);
  transpose_w<<<256 ,256,0,stream>>>(WtQKV, Wv_t, 256 ,256 , 768 , 512);
  transpose_w<<<256 ,256,0,stream>>>(WtWO , Wo  , 256 ,256 , 256 , 0  );
  transpose_w<<<1024,256,0,stream>>>(WtF1A, f1w1, 1024,256 , 1024, 0  );
  transpose_w<<<1024,256,0,stream>>>(WtF1B, f1w2, 256 ,1024, 256 , 0  );
  transpose_w<<<1024,256,0,stream>>>(WtS  , Wq_s, 512 ,512 , 1024, 0  );
  transpose_w<<<1024,256,0,stream>>>(WtS  , Wk_s, 512 ,512 , 1024, 512);
  transpose_w<<<1024,256,0,stream>>>(WtF2A, f2w1, 1024,256 , 1024, 0  );
  transpose_w<<<1024,256,0,stream>>>(WtF2B, f2w2, 256 ,1024, 256 , 0  );

  // 1. h = LN(x_T)
  ln_kernel<<<8192,256,0,stream>>>(bufH, x_T, tl1w, tl1b, 256);
  // 2. qkv = h @ [Wq|Wk|Wv]^T
  gemm_k<<<dim3(128,12,1),256,0,stream>>>(bufH, WtQKV, bufBig,
        nullptr, nullptr, 8192,768,256, 0, 0,0,0,0);
  // 3. temporal causal attention -> o
  temporal_attn<<<dim3(512,8,16),256,0,stream>>>(bufBig, bufO);
  // 4. x = o @ Wo^T + x_T
  gemm_k<<<dim3(128,4,1),256,0,stream>>>(bufO, WtWO, bufX,
        nullptr, x_T, 8192,256,256, F_RES, 0,0,0,0);
  // 5. h2 = LN(x)
  ln_kernel<<<8192,256,0,stream>>>(bufH, bufX, tl2w, tl2b, 256);
  // 6. f1 = relu(h2 @ w1^T + b1)
  gemm_k<<<dim3(128,16,1),256,0,stream>>>(bufH, WtF1A, bufBig,
        f1b1, nullptr, 8192,1024,256, F_BIAS|F_RELU, 0,0,0,0);
  // 7. temporal_out = f1 @ w2^T + b2 + x
  gemm_k<<<dim3(128,4,1),256,0,stream>>>(bufBig, WtF1B, bufTO,
        f1b2, bufX, 8192,256,1024, F_BIAS|F_RES, 0,0,0,0);
  // 8. hs = LN(x_S) over T
  ln_kernel<<<4096,256,0,stream>>>(bufH, x_S, sl1w, sl1b, 512);
  // 9. [qs|ks] = hs @ [Wq_s|Wk_s]^T
  gemm_k<<<dim3(64,16,1),256,0,stream>>>(bufH, WtS, bufBig,
        nullptr, nullptr, 4096,1024,512, 0, 0,0,0,0);
  // 10. spatial softmax + head-mean -> swT (fp32) and spatial_weights (out1)
  spatial_attn<<<dim3(256,16),256,0,stream>>>(bufBig, swT, out1);
  // 11. x2 = TO @ swT[b] + TO   (batched over b)
  gemm_k<<<dim3(8,4,16),256,0,stream>>>(bufTO, swT, bufX2,
        nullptr, bufTO, 512,256,256, F_RES,
        131072, 65536, 131072, 131072);
  // 12. h3 = LN(x2)
  ln_kernel<<<8192,256,0,stream>>>(bufH, bufX2, flw, flb, 256);
  // 13. f2 hidden
  gemm_k<<<dim3(128,16,1),256,0,stream>>>(bufH, WtF2A, bufBig,
        f2b1, nullptr, 8192,1024,256, F_BIAS|F_RELU, 0,0,0,0);
  // 14. out = f2 @ w2^T + b2 + x2  (fp32 store to d_out)
  gemm_k<<<dim3(128,4,1),256,0,stream>>>(bufBig, WtF2B, out0,
        f2b2, bufX2, 8192,256,1024, F_BIAS|F_RES, 0,0,0,0);
}

// Round 3
// 933.422 us; speedup vs baseline: 1.7530x; 1.7530x over previous
//
#include <hip/hip_runtime.h>
#include <hip/hip_bf16.h>

#define F_BIAS 1
#define F_RELU 2
#define F_RES  4

// dst[k*dstStride + colOff + j] = src[j*K + k]   (src: [J rows, K cols] fp32)
__global__ void transpose_w(float* __restrict__ dst, const float* __restrict__ src,
                            int J, int K, int dstStride, int colOff){
  int idx = blockIdx.x*256 + threadIdx.x;
  if (idx >= J*K) return;
  int j = idx / K, k = idx - j*K;
  dst[(size_t)k*dstStride + colOff + j] = src[idx];
}

// Row LayerNorm: one block per row, 256 threads, rowLen in {256, 512}
__global__ __launch_bounds__(256) void ln_kernel(float* __restrict__ dst,
    const float* __restrict__ src, const float* __restrict__ w,
    const float* __restrict__ bvec, int rowLen){
  int row = blockIdx.x, tid = threadIdx.x;
  const float* s = src + (size_t)row*rowLen;
  float x0 = s[tid];
  float x1 = (rowLen > 256) ? s[tid+256] : 0.0f;
  float sum = x0 + x1, sq = x0*x0 + x1*x1;
  #pragma unroll
  for (int off=32; off; off>>=1){
    sum += __shfl_down(sum, off, 64);
    sq  += __shfl_down(sq , off, 64);
  }
  __shared__ float sbs[4], sbq[4];
  int wid = tid>>6, lane = tid&63;
  if (lane==0){ sbs[wid]=sum; sbq[wid]=sq; }
  __syncthreads();
  if (tid==0){
    float a=0, b2=0;
    for (int i=0;i<4;i++){ a+=sbs[i]; b2+=sbq[i]; }
    sbs[0]=a; sbq[0]=b2;
  }
  __syncthreads();
  float inv  = 1.0f/(float)rowLen;
  float mean = sbs[0]*inv;
  float var  = sbq[0]*inv - mean*mean;
  float rstd = rsqrtf(var + 1e-6f);
  float* d = dst + (size_t)row*rowLen;
  d[tid] = (x0-mean)*rstd*w[tid] + bvec[tid];
  if (rowLen > 256)
    d[tid+256] = (x1-mean)*rstd*w[tid+256] + bvec[tid+256];
}

// C[M,N] = A[M,K] @ Bt[K,N] (+bias)(relu)(+resid). Batched via grid.z.
// M%64==0, N%64==0, K%16==0.
__global__ __launch_bounds__(256) void gemm_k(
    const float* __restrict__ A, const float* __restrict__ Bt,
    float* __restrict__ outC,
    const float* __restrict__ bias, const float* __restrict__ resid,
    int M, int N, int K, int flags,
    long long strideA, long long strideB, long long strideO, long long strideR){
  int bz = blockIdx.z;
  A  += (size_t)bz*strideA;
  Bt += (size_t)bz*strideB;
  __shared__ float As[16][68];
  __shared__ float Bs[16][68];
  int tid = threadIdx.x;
  int m0 = blockIdx.x*64, n0 = blockIdx.y*64;
  int tx = tid & 15, ty = tid >> 4;
  int lr = tid & 63, lk = tid >> 6;
  float acc[4][4] = {{0.0f}};
  for (int k0 = 0; k0 < K; k0 += 16){
    const float* ap = A + (size_t)(m0+lr)*K + k0 + lk*4;
    float4 av = *(const float4*)ap;
    As[lk*4+0][lr] = av.x; As[lk*4+1][lr] = av.y;
    As[lk*4+2][lr] = av.z; As[lk*4+3][lr] = av.w;
    #pragma unroll
    for (int q=0;q<4;q++)
      Bs[lk*4+q][lr] = Bt[(size_t)(k0+lk*4+q)*N + n0 + lr];
    __syncthreads();
    #pragma unroll
    for (int k=0;k<16;k++){
      float a0=As[k][ty*4+0], a1=As[k][ty*4+1], a2=As[k][ty*4+2], a3=As[k][ty*4+3];
      float b0=Bs[k][tx*4+0], b1=Bs[k][tx*4+1], b2=Bs[k][tx*4+2], b3=Bs[k][tx*4+3];
      acc[0][0]+=a0*b0; acc[0][1]+=a0*b1; acc[0][2]+=a0*b2; acc[0][3]+=a0*b3;
      acc[1][0]+=a1*b0; acc[1][1]+=a1*b1; acc[1][2]+=a1*b2; acc[1][3]+=a1*b3;
      acc[2][0]+=a2*b0; acc[2][1]+=a2*b1; acc[2][2]+=a2*b2; acc[2][3]+=a2*b3;
      acc[3][0]+=a3*b0; acc[3][1]+=a3*b1; acc[3][2]+=a3*b2; acc[3][3]+=a3*b3;
    }
    __syncthreads();
  }
  #pragma unroll
  for (int i=0;i<4;i++){
    int r = m0 + ty*4 + i;
    #pragma unroll
    for (int j=0;j<4;j++){
      int c = n0 + tx*4 + j;
      float v = acc[i][j];
      if (flags & F_BIAS) v += bias[c];
      if (flags & F_RELU) v = fmaxf(v, 0.0f);
      if (flags & F_RES)
        v += resid[(size_t)bz*strideR + (size_t)r*N + c];
      outC[(size_t)bz*strideO + (size_t)r*N + c] = v;
    }
  }
}

// Flash-style temporal causal attention.
// qkv layout: row = b*512+t (stride 768), cols [0:256)=q, [256:512)=k,
// [512:768)=v, each col = h*32+d.
// One block per (qtile=64 queries, h, b). 256 threads as 16x16:
//   thread (tx,ty) owns S rows ty*4..+3 (queries), S cols tx*4..+3 (keys),
//   O cols tx*2..+1 (head dims), online softmax state per owned row.
__global__ __launch_bounds__(256) void flash_tattn(
    const float* __restrict__ qkv, float* __restrict__ o){
  int qt = blockIdx.x, h = blockIdx.y, b = blockIdx.z;
  int tid = threadIdx.x;
  int tx = tid & 15, ty = tid >> 4;
  __shared__ float Qs[64][33];
  __shared__ float Ks[64][33];
  __shared__ float Vs[64][33];
  __shared__ float Ps[64][65];
  const float* base = qkv + (size_t)b*512*768;
  int t0 = qt*64;
  const float scale = 0.17677669529663687f; // 1/sqrt(32)
  // stage Q tile (scaled). 512 float4s over 256 threads.
  for (int i = tid; i < 512; i += 256){
    int row = i>>3, c0 = (i&7)*4;
    float4 f = *(const float4*)(base + (size_t)(t0+row)*768 + h*32 + c0);
    Qs[row][c0+0]=f.x*scale; Qs[row][c0+1]=f.y*scale;
    Qs[row][c0+2]=f.z*scale; Qs[row][c0+3]=f.w*scale;
  }
  float m_i[4], l_i[4], Oc[4][2];
  #pragma unroll
  for (int i=0;i<4;i++){ m_i[i]=-3.0e38f; l_i[i]=0.0f; Oc[i][0]=0.0f; Oc[i][1]=0.0f; }

  for (int kt = 0; kt <= qt; ++kt){
    int s0 = kt*64;
    __syncthreads();   // Q staged / previous-iter Ps,Vs readers done
    for (int i = tid; i < 512; i += 256){
      int row = i>>3, c0 = (i&7)*4;
      const float* rp = base + (size_t)(s0+row)*768 + h*32 + c0;
      float4 fk = *(const float4*)(rp + 256);
      float4 fv = *(const float4*)(rp + 512);
      Ks[row][c0+0]=fk.x; Ks[row][c0+1]=fk.y; Ks[row][c0+2]=fk.z; Ks[row][c0+3]=fk.w;
      Vs[row][c0+0]=fv.x; Vs[row][c0+1]=fv.y; Vs[row][c0+2]=fv.z; Vs[row][c0+3]=fv.w;
    }
    __syncthreads();
    // S tile 4x4 per thread
    float s4[4][4] = {{0.0f}};
    #pragma unroll 4
    for (int d=0; d<32; ++d){
      float qv[4], kv[4];
      #pragma unroll
      for (int i=0;i<4;i++) qv[i] = Qs[ty*4+i][d];
      #pragma unroll
      for (int j=0;j<4;j++) kv[j] = Ks[tx*4+j][d];
      #pragma unroll
      for (int i=0;i<4;i++)
        #pragma unroll
        for (int j=0;j<4;j++)
          s4[i][j] += qv[i]*kv[j];
    }
    if (kt == qt){   // causal mask on diagonal tile (local: key > query)
      #pragma unroll
      for (int i=0;i<4;i++){
        int qg = ty*4+i;
        #pragma unroll
        for (int j=0;j<4;j++)
          if (tx*4+j > qg) s4[i][j] = -3.0e38f;
      }
    }
    // online softmax per owned row; reduce across the 16 tx lanes
    #pragma unroll
    for (int i=0;i<4;i++){
      float mx = fmaxf(fmaxf(s4[i][0],s4[i][1]), fmaxf(s4[i][2],s4[i][3]));
      #pragma unroll
      for (int off=1; off<16; off<<=1) mx = fmaxf(mx, __shfl_xor(mx, off, 16));
      float m_new = fmaxf(m_i[i], mx);
      float alpha = __expf(m_i[i]-m_new);
      float rs = 0.0f;
      #pragma unroll
      for (int j=0;j<4;j++){
        float p = __expf(s4[i][j]-m_new);
        s4[i][j] = p; rs += p;
      }
      #pragma unroll
      for (int off=1; off<16; off<<=1) rs += __shfl_xor(rs, off, 16);
      l_i[i] = l_i[i]*alpha + rs;
      m_i[i] = m_new;
      Oc[i][0] *= alpha; Oc[i][1] *= alpha;
      Ps[ty*4+i][tx*4+0]=s4[i][0]; Ps[ty*4+i][tx*4+1]=s4[i][1];
      Ps[ty*4+i][tx*4+2]=s4[i][2]; Ps[ty*4+i][tx*4+3]=s4[i][3];
    }
    __syncthreads();
    // O += P @ V  (thread: 4 rows x 2 dims)
    #pragma unroll 4
    for (int k=0;k<64;++k){
      float v0 = Vs[k][tx*2], v1 = Vs[k][tx*2+1];
      #pragma unroll
      for (int i=0;i<4;i++){
        float p = Ps[ty*4+i][k];
        Oc[i][0] += p*v0; Oc[i][1] += p*v1;
      }
    }
  }
  #pragma unroll
  for (int i=0;i<4;i++){
    float inv = 1.0f/l_i[i];
    int t = t0 + ty*4 + i;
    float* op = o + ((size_t)(b*512+t))*256 + h*32 + tx*2;
    op[0] = Oc[i][0]*inv; op[1] = Oc[i][1]*inv;
  }
}

// Spatial attention. qk layout: row = b*256+c (stride 1024),
// cols [0:512)=qs (h*64+d), [512:1024)=ks. One block per (c,b); thread = e.
// sw[b,c,e] = mean_h softmax_e( qs[b,c,h,:]·ks[b,e,h,:] / 8 )
// Writes fp32 sw to out1 and fp32 swT[b][e][c] for the fusion GEMM.
__global__ __launch_bounds__(256) void spatial_attn(
    const float* __restrict__ qk, float* __restrict__ swT,
    float* __restrict__ swOut){
  int c = blockIdx.x, b = blockIdx.y, e = threadIdx.x;
  __shared__ float qsh[64];
  __shared__ float rbuf[4];
  const float* qrow = qk + ((size_t)(b*256+c))*1024;
  const float* krow = qk + ((size_t)(b*256+e))*1024 + 512;
  int wid = e>>6, lane = e&63;
  float acc = 0.0f;
  for (int h=0; h<8; ++h){
    __syncthreads();
    if (e < 64) qsh[e] = qrow[h*64 + e];
    __syncthreads();
    const float* kp = krow + h*64;
    float s = 0.0f;
    #pragma unroll
    for (int d=0; d<64; d++) s += qsh[d]*kp[d];
    s *= 0.125f;
    float m = s;
    #pragma unroll
    for (int off=32; off; off>>=1) m = fmaxf(m, __shfl_down(m, off, 64));
    if (lane==0) rbuf[wid]=m;
    __syncthreads();
    if (e==0){ float mm=rbuf[0]; for(int i=1;i<4;i++) mm=fmaxf(mm,rbuf[i]); rbuf[0]=mm; }
    __syncthreads();
    float Mx = rbuf[0];
    __syncthreads();
    float ex = __expf(s-Mx);
    float ss = ex;
    #pragma unroll
    for (int off=32; off; off>>=1) ss += __shfl_down(ss, off, 64);
    if (lane==0) rbuf[wid]=ss;
    __syncthreads();
    if (e==0){ float s2=0; for(int i=0;i<4;i++) s2+=rbuf[i]; rbuf[0]=s2; }
    __syncthreads();
    acc += ex / rbuf[0] * 0.125f;
  }
  swT[((size_t)(b*256) + e)*256 + c] = acc;
  swOut[((size_t)(b*256) + c)*256 + e] = acc;
}

extern "C" void kernel_launch(void* const* d_in, const int* in_sizes, int n_in,
                              void* d_out, int out_size, void* d_ws, size_t ws_size,
                              hipStream_t stream){
  (void)in_sizes; (void)n_in; (void)out_size; (void)ws_size;
  const float* x_T  = (const float*)d_in[0];
  const float* x_S  = (const float*)d_in[1];
  const float* Wq_t = (const float*)d_in[2];
  const float* Wk_t = (const float*)d_in[3];
  const float* Wv_t = (const float*)d_in[4];
  const float* Wo   = (const float*)d_in[5];
  const float* Wq_s = (const float*)d_in[6];
  const float* Wk_s = (const float*)d_in[7];
  const float* f1w1 = (const float*)d_in[8];
  const float* f1b1 = (const float*)d_in[9];
  const float* f1w2 = (const float*)d_in[10];
  const float* f1b2 = (const float*)d_in[11];
  const float* f2w1 = (const float*)d_in[12];
  const float* f2b1 = (const float*)d_in[13];
  const float* f2w2 = (const float*)d_in[14];
  const float* f2b2 = (const float*)d_in[15];
  const float* tl1w = (const float*)d_in[16];
  const float* tl1b = (const float*)d_in[17];
  const float* tl2w = (const float*)d_in[18];
  const float* tl2b = (const float*)d_in[19];
  const float* sl1w = (const float*)d_in[20];
  const float* sl1b = (const float*)d_in[21];
  const float* flw  = (const float*)d_in[22];
  const float* flb  = (const float*)d_in[23];

  float* ws = (float*)d_ws;
  size_t off = 0;
  float* WtQKV = ws + off; off += 256*768;
  float* WtWO  = ws + off; off += 256*256;
  float* WtF1A = ws + off; off += 256*1024;
  float* WtF1B = ws + off; off += 1024*256;
  float* WtS   = ws + off; off += 512*1024;
  float* WtF2A = ws + off; off += 256*1024;
  float* WtF2B = ws + off; off += 1024*256;
  float* bufH  = ws + off; off += (size_t)8192*256;
  float* bufBig= ws + off; off += (size_t)8192*1024;
  float* bufO  = ws + off; off += (size_t)8192*256;
  float* bufX  = ws + off; off += (size_t)8192*256;
  float* bufTO = ws + off; off += (size_t)8192*256;
  float* bufX2 = ws + off; off += (size_t)8192*256;
  float* swT   = ws + off; off += (size_t)16*256*256;

  float* out0 = (float*)d_out;                      // [B,T,C]
  float* out1 = out0 + (size_t)16*512*256;          // spatial_weights [B,C,C]

  // ---- weight transposes (fp32 [J,K] -> fp32 [K x N]) ----
  transpose_w<<<256 ,256,0,stream>>>(WtQKV, Wq_t, 256 ,256 , 768 , 0  );
  transpose_w<<<256 ,256,0,stream>>>(WtQKV, Wk_t, 256 ,256 , 768 , 256);
  transpose_w<<<256 ,256,0,stream>>>(WtQKV, Wv_t, 256 ,256 , 768 , 512);
  transpose_w<<<256 ,256,0,stream>>>(WtWO , Wo  , 256 ,256 , 256 , 0  );
  transpose_w<<<1024,256,0,stream>>>(WtF1A, f1w1, 1024,256 , 1024, 0  );
  transpose_w<<<1024,256,0,stream>>>(WtF1B, f1w2, 256 ,1024, 256 , 0  );
  transpose_w<<<1024,256,0,stream>>>(WtS  , Wq_s, 512 ,512 , 1024, 0  );
  transpose_w<<<1024,256,0,stream>>>(WtS  , Wk_s, 512 ,512 , 1024, 512);
  transpose_w<<<1024,256,0,stream>>>(WtF2A, f2w1, 1024,256 , 1024, 0  );
  transpose_w<<<1024,256,0,stream>>>(WtF2B, f2w2, 256 ,1024, 256 , 0  );

  // 1. h = LN(x_T)
  ln_kernel<<<8192,256,0,stream>>>(bufH, x_T, tl1w, tl1b, 256);
  // 2. qkv = h @ [Wq|Wk|Wv]^T
  gemm_k<<<dim3(128,12,1),256,0,stream>>>(bufH, WtQKV, bufBig,
        nullptr, nullptr, 8192,768,256, 0, 0,0,0,0);
  // 3. temporal causal attention (flash) -> o
  flash_tattn<<<dim3(8,8,16),256,0,stream>>>(bufBig, bufO);
  // 4. x = o @ Wo^T + x_T
  gemm_k<<<dim3(128,4,1),256,0,stream>>>(bufO, WtWO, bufX,
        nullptr, x_T, 8192,256,256, F_RES, 0,0,0,0);
  // 5. h2 = LN(x)
  ln_kernel<<<8192,256,0,stream>>>(bufH, bufX, tl2w, tl2b, 256);
  // 6. f1 = relu(h2 @ w1^T + b1)
  gemm_k<<<dim3(128,16,1),256,0,stream>>>(bufH, WtF1A, bufBig,
        f1b1, nullptr, 8192,1024,256, F_BIAS|F_RELU, 0,0,0,0);
  // 7. temporal_out = f1 @ w2^T + b2 + x
  gemm_k<<<dim3(128,4,1),256,0,stream>>>(bufBig, WtF1B, bufTO,
        f1b2, bufX, 8192,256,1024, F_BIAS|F_RES, 0,0,0,0);
  // 8. hs = LN(x_S) over T
  ln_kernel<<<4096,256,0,stream>>>(bufH, x_S, sl1w, sl1b, 512);
  // 9. [qs|ks] = hs @ [Wq_s|Wk_s]^T
  gemm_k<<<dim3(64,16,1),256,0,stream>>>(bufH, WtS, bufBig,
        nullptr, nullptr, 4096,1024,512, 0, 0,0,0,0);
  // 10. spatial softmax + head-mean -> swT (fp32) and spatial_weights (out1)
  spatial_attn<<<dim3(256,16),256,0,stream>>>(bufBig, swT, out1);
  // 11. x2 = TO @ swT[b] + TO   (batched over b)
  gemm_k<<<dim3(8,4,16),256,0,stream>>>(bufTO, swT, bufX2,
        nullptr, bufTO, 512,256,256, F_RES,
        131072, 65536, 131072, 131072);
  // 12. h3 = LN(x2)
  ln_kernel<<<8192,256,0,stream>>>(bufH, bufX2, flw, flb, 256);
  // 13. f2 hidden
  gemm_k<<<dim3(128,16,1),256,0,stream>>>(bufH, WtF2A, bufBig,
        f2b1, nullptr, 8192,1024,256, F_BIAS|F_RELU, 0,0,0,0);
  // 14. out = f2 @ w2^T + b2 + x2  (fp32 store to d_out)
  gemm_k<<<dim3(128,4,1),256,0,stream>>>(bufBig, WtF2B, out0,
        f2b2, bufX2, 8192,256,1024, F_BIAS|F_RES, 0,0,0,0);
}

// Round 4
// 569.732 us; speedup vs baseline: 2.8721x; 1.6384x over previous
//
#include <hip/hip_runtime.h>
#include <hip/hip_bf16.h>

typedef __hip_bfloat16 bf16;
typedef __attribute__((ext_vector_type(8))) short short8;
typedef __attribute__((ext_vector_type(4))) float f32x4;

#define F_BIAS 1
#define F_RELU 2
#define F_RES  4

__device__ __forceinline__ void st_out(float* p, float v){ *p = v; }
__device__ __forceinline__ void st_out(bf16* p, float v){ *p = __float2bfloat16(v); }

// fp32 -> bf16 elementwise
__global__ void to_bf16(bf16* __restrict__ dst, const float* __restrict__ src, int n){
  int i = blockIdx.x*256 + threadIdx.x;
  if (i < n) dst[i] = __float2bfloat16(src[i]);
}

// dst[k*dstStride + colOff + j] = src[j*K + k]   (fp32, for spatial path only)
__global__ void transpose_w(float* __restrict__ dst, const float* __restrict__ src,
                            int J, int K, int dstStride, int colOff){
  int idx = blockIdx.x*256 + threadIdx.x;
  if (idx >= J*K) return;
  int j = idx / K, k = idx - j*K;
  dst[(size_t)k*dstStride + colOff + j] = src[idx];
}

// Row LayerNorm: one block per row, 256 threads, rowLen in {256, 512}.
// OutT = bf16 for MFMA consumers, float for the fp32 spatial path.
template <typename OutT>
__global__ __launch_bounds__(256) void ln_kernel(OutT* __restrict__ dst,
    const float* __restrict__ src, const float* __restrict__ w,
    const float* __restrict__ bvec, int rowLen){
  int row = blockIdx.x, tid = threadIdx.x;
  const float* s = src + (size_t)row*rowLen;
  float x0 = s[tid];
  float x1 = (rowLen > 256) ? s[tid+256] : 0.0f;
  float sum = x0 + x1, sq = x0*x0 + x1*x1;
  #pragma unroll
  for (int off=32; off; off>>=1){
    sum += __shfl_down(sum, off, 64);
    sq  += __shfl_down(sq , off, 64);
  }
  __shared__ float sbs[4], sbq[4];
  int wid = tid>>6, lane = tid&63;
  if (lane==0){ sbs[wid]=sum; sbq[wid]=sq; }
  __syncthreads();
  if (tid==0){
    float a=0, b2=0;
    for (int i=0;i<4;i++){ a+=sbs[i]; b2+=sbq[i]; }
    sbs[0]=a; sbq[0]=b2;
  }
  __syncthreads();
  float inv  = 1.0f/(float)rowLen;
  float mean = sbs[0]*inv;
  float var  = sbq[0]*inv - mean*mean;
  float rstd = rsqrtf(var + 1e-6f);
  OutT* d = dst + (size_t)row*rowLen;
  st_out(&d[tid], (x0-mean)*rstd*w[tid] + bvec[tid]);
  if (rowLen > 256)
    st_out(&d[tid+256], (x1-mean)*rstd*w[tid+256] + bvec[tid+256]);
}

// ---------------- MFMA bf16 GEMM ----------------
// C[M,N] = A[M,K](bf16) @ B[N,K](bf16)^T  (+bias fp32)(relu)(+resid fp32)
// Tile: M=128 x N=64, 128 threads = 2 waves, each wave a 64x64 subtile via
// 4x4 grid of mfma_f32_16x16x32_bf16. Fragment layouts per verified guide:
//   A/B lane: [idx=lane&15][k=(lane>>4)*8+j]; C/D: col=lane&15,row=quad*4+reg.
// Requires M%128==0, N%64==0, K%32==0.
__global__ __launch_bounds__(128) void gemm_mfma(
    const bf16* __restrict__ A, const bf16* __restrict__ B,
    float* __restrict__ outF, bf16* __restrict__ outB,
    const float* __restrict__ bias, const float* __restrict__ resid,
    int M, int N, int K, int flags,
    long long sA, long long sB, long long sO, long long sR){
  int bz = blockIdx.z;
  A += (size_t)bz*sA;
  B += (size_t)bz*sB;
  __shared__ short As[128*32];
  __shared__ short Bs[64*32];
  int tid = threadIdx.x;
  int m0 = blockIdx.x*128, n0 = blockIdx.y*64;
  int w = tid >> 6, lane = tid & 63;
  int quad = lane >> 4, l16 = lane & 15;
  f32x4 acc[4][4];
  #pragma unroll
  for (int r=0;r<4;r++)
    #pragma unroll
    for (int j=0;j<4;j++)
      acc[r][j] = (f32x4){0.f,0.f,0.f,0.f};

  for (int k0 = 0; k0 < K; k0 += 32){
    #pragma unroll
    for (int c=0;c<4;c++){            // A tile: 128x32 bf16
      int i = tid + c*128;            // chunk 0..511 (8 bf16 each)
      int row = i >> 2, c0 = (i & 3)*8;
      *(short8*)&As[row*32 + c0] =
        *(const short8*)(A + (size_t)(m0+row)*K + k0 + c0);
    }
    #pragma unroll
    for (int c=0;c<2;c++){            // B tile: 64x32 bf16
      int i = tid + c*128;            // chunk 0..255
      int row = i >> 2, c0 = (i & 3)*8;
      *(short8*)&Bs[row*32 + c0] =
        *(const short8*)(B + (size_t)(n0+row)*K + k0 + c0);
    }
    __syncthreads();
    short8 af[4], bfr[4];
    #pragma unroll
    for (int r=0;r<4;r++) af[r]  = *(short8*)&As[(w*64 + r*16 + l16)*32 + quad*8];
    #pragma unroll
    for (int j=0;j<4;j++) bfr[j] = *(short8*)&Bs[(j*16 + l16)*32 + quad*8];
    #pragma unroll
    for (int r=0;r<4;r++)
      #pragma unroll
      for (int j=0;j<4;j++)
        acc[r][j] = __builtin_amdgcn_mfma_f32_16x16x32_bf16(af[r], bfr[j], acc[r][j], 0,0,0);
    __syncthreads();
  }
  #pragma unroll
  for (int r=0;r<4;r++){
    int mb = m0 + w*64 + r*16 + quad*4;
    #pragma unroll
    for (int j=0;j<4;j++){
      int n = n0 + j*16 + l16;
      float bv = (flags & F_BIAS) ? bias[n] : 0.0f;
      #pragma unroll
      for (int e=0;e<4;e++){
        float v = acc[r][j][e] + bv;
        if (flags & F_RELU) v = fmaxf(v, 0.0f);
        size_t idx = (size_t)(mb+e)*N + n;
        if (flags & F_RES) v += resid[(size_t)bz*sR + idx];
        if (outF) outF[(size_t)bz*sO + idx] = v;
        if (outB) st_out(outB + (size_t)bz*sO + idx, v);
      }
    }
  }
}

// fp32 LDS-tiled GEMM (spatial projection path only).
__global__ __launch_bounds__(256) void gemm_k(
    const float* __restrict__ A, const float* __restrict__ Bt,
    float* __restrict__ outC,
    const float* __restrict__ bias, const float* __restrict__ resid,
    int M, int N, int K, int flags){
  __shared__ float As[16][68];
  __shared__ float Bs[16][68];
  int tid = threadIdx.x;
  int m0 = blockIdx.x*64, n0 = blockIdx.y*64;
  int tx = tid & 15, ty = tid >> 4;
  int lr = tid & 63, lk = tid >> 6;
  float acc[4][4] = {{0.0f}};
  for (int k0 = 0; k0 < K; k0 += 16){
    const float* ap = A + (size_t)(m0+lr)*K + k0 + lk*4;
    float4 av = *(const float4*)ap;
    As[lk*4+0][lr] = av.x; As[lk*4+1][lr] = av.y;
    As[lk*4+2][lr] = av.z; As[lk*4+3][lr] = av.w;
    #pragma unroll
    for (int q=0;q<4;q++)
      Bs[lk*4+q][lr] = Bt[(size_t)(k0+lk*4+q)*N + n0 + lr];
    __syncthreads();
    #pragma unroll
    for (int k=0;k<16;k++){
      float a0=As[k][ty*4+0], a1=As[k][ty*4+1], a2=As[k][ty*4+2], a3=As[k][ty*4+3];
      float b0=Bs[k][tx*4+0], b1=Bs[k][tx*4+1], b2=Bs[k][tx*4+2], b3=Bs[k][tx*4+3];
      acc[0][0]+=a0*b0; acc[0][1]+=a0*b1; acc[0][2]+=a0*b2; acc[0][3]+=a0*b3;
      acc[1][0]+=a1*b0; acc[1][1]+=a1*b1; acc[1][2]+=a1*b2; acc[1][3]+=a1*b3;
      acc[2][0]+=a2*b0; acc[2][1]+=a2*b1; acc[2][2]+=a2*b2; acc[2][3]+=a2*b3;
      acc[3][0]+=a3*b0; acc[3][1]+=a3*b1; acc[3][2]+=a3*b2; acc[3][3]+=a3*b3;
    }
    __syncthreads();
  }
  #pragma unroll
  for (int i=0;i<4;i++){
    int r = m0 + ty*4 + i;
    #pragma unroll
    for (int j=0;j<4;j++){
      int c = n0 + tx*4 + j;
      float v = acc[i][j];
      if (flags & F_BIAS) v += bias[c];
      if (flags & F_RELU) v = fmaxf(v, 0.0f);
      if (flags & F_RES)  v += resid[(size_t)r*N + c];
      outC[(size_t)r*N + c] = v;
    }
  }
}

// Flash-style temporal causal attention (writes bf16 for the MFMA Wo GEMM).
__global__ __launch_bounds__(256) void flash_tattn(
    const float* __restrict__ qkv, bf16* __restrict__ o){
  int qt = blockIdx.x, h = blockIdx.y, b = blockIdx.z;
  int tid = threadIdx.x;
  int tx = tid & 15, ty = tid >> 4;
  __shared__ float Qs[64][33];
  __shared__ float Ks[64][33];
  __shared__ float Vs[64][33];
  __shared__ float Ps[64][65];
  const float* base = qkv + (size_t)b*512*768;
  int t0 = qt*64;
  const float scale = 0.17677669529663687f; // 1/sqrt(32)
  for (int i = tid; i < 512; i += 256){
    int row = i>>3, c0 = (i&7)*4;
    float4 f = *(const float4*)(base + (size_t)(t0+row)*768 + h*32 + c0);
    Qs[row][c0+0]=f.x*scale; Qs[row][c0+1]=f.y*scale;
    Qs[row][c0+2]=f.z*scale; Qs[row][c0+3]=f.w*scale;
  }
  float m_i[4], l_i[4], Oc[4][2];
  #pragma unroll
  for (int i=0;i<4;i++){ m_i[i]=-3.0e38f; l_i[i]=0.0f; Oc[i][0]=0.0f; Oc[i][1]=0.0f; }

  for (int kt = 0; kt <= qt; ++kt){
    int s0 = kt*64;
    __syncthreads();
    for (int i = tid; i < 512; i += 256){
      int row = i>>3, c0 = (i&7)*4;
      const float* rp = base + (size_t)(s0+row)*768 + h*32 + c0;
      float4 fk = *(const float4*)(rp + 256);
      float4 fv = *(const float4*)(rp + 512);
      Ks[row][c0+0]=fk.x; Ks[row][c0+1]=fk.y; Ks[row][c0+2]=fk.z; Ks[row][c0+3]=fk.w;
      Vs[row][c0+0]=fv.x; Vs[row][c0+1]=fv.y; Vs[row][c0+2]=fv.z; Vs[row][c0+3]=fv.w;
    }
    __syncthreads();
    float s4[4][4] = {{0.0f}};
    #pragma unroll 4
    for (int d=0; d<32; ++d){
      float qv[4], kv[4];
      #pragma unroll
      for (int i=0;i<4;i++) qv[i] = Qs[ty*4+i][d];
      #pragma unroll
      for (int j=0;j<4;j++) kv[j] = Ks[tx*4+j][d];
      #pragma unroll
      for (int i=0;i<4;i++)
        #pragma unroll
        for (int j=0;j<4;j++)
          s4[i][j] += qv[i]*kv[j];
    }
    if (kt == qt){
      #pragma unroll
      for (int i=0;i<4;i++){
        int qg = ty*4+i;
        #pragma unroll
        for (int j=0;j<4;j++)
          if (tx*4+j > qg) s4[i][j] = -3.0e38f;
      }
    }
    #pragma unroll
    for (int i=0;i<4;i++){
      float mx = fmaxf(fmaxf(s4[i][0],s4[i][1]), fmaxf(s4[i][2],s4[i][3]));
      #pragma unroll
      for (int off=1; off<16; off<<=1) mx = fmaxf(mx, __shfl_xor(mx, off, 16));
      float m_new = fmaxf(m_i[i], mx);
      float alpha = __expf(m_i[i]-m_new);
      float rs = 0.0f;
      #pragma unroll
      for (int j=0;j<4;j++){
        float p = __expf(s4[i][j]-m_new);
        s4[i][j] = p; rs += p;
      }
      #pragma unroll
      for (int off=1; off<16; off<<=1) rs += __shfl_xor(rs, off, 16);
      l_i[i] = l_i[i]*alpha + rs;
      m_i[i] = m_new;
      Oc[i][0] *= alpha; Oc[i][1] *= alpha;
      Ps[ty*4+i][tx*4+0]=s4[i][0]; Ps[ty*4+i][tx*4+1]=s4[i][1];
      Ps[ty*4+i][tx*4+2]=s4[i][2]; Ps[ty*4+i][tx*4+3]=s4[i][3];
    }
    __syncthreads();
    #pragma unroll 4
    for (int k=0;k<64;++k){
      float v0 = Vs[k][tx*2], v1 = Vs[k][tx*2+1];
      #pragma unroll
      for (int i=0;i<4;i++){
        float p = Ps[ty*4+i][k];
        Oc[i][0] += p*v0; Oc[i][1] += p*v1;
      }
    }
  }
  #pragma unroll
  for (int i=0;i<4;i++){
    float inv = 1.0f/l_i[i];
    int t = t0 + ty*4 + i;
    bf16* op = o + ((size_t)(b*512+t))*256 + h*32 + tx*2;
    op[0] = __float2bfloat16(Oc[i][0]*inv);
    op[1] = __float2bfloat16(Oc[i][1]*inv);
  }
}

// Tiled spatial attention, partial over a 4-head group.
// qk: row = b*256+c (stride 1024), cols [0:512)=qs (h*64+d), [512:1024)=ks.
// grid (ct=8, b=16, hg=2), 256 threads: tx=tid&31 (e groups), ty=tid>>5 (4 c-rows).
// Pout[hg][b][c][e] = sum_{h in group} softmax_e(q_c . k_e / 8)
__global__ __launch_bounds__(256) void spatial_attn2(
    const float* __restrict__ qk, float* __restrict__ Pout){
  int ct = blockIdx.x, b = blockIdx.y, hg = blockIdx.z;
  int tid = threadIdx.x;
  int tx = tid & 31, ty = tid >> 5;
  __shared__ float Qs[32][64];
  __shared__ float Ks[256][36];
  float fRes[4][8];
  #pragma unroll
  for (int r=0;r<4;r++)
    #pragma unroll
    for (int j=0;j<8;j++) fRes[r][j] = 0.0f;

  for (int hh=0; hh<4; ++hh){
    int h = hg*4 + hh;
    float sreg[4][8];
    #pragma unroll
    for (int r=0;r<4;r++)
      #pragma unroll
      for (int j=0;j<8;j++) sreg[r][j] = 0.0f;
    for (int dh=0; dh<2; ++dh){
      __syncthreads();
      if (dh==0){
        for (int i=tid; i<512; i+=256){   // Q tile 32x64
          int row = i>>4, c0 = (i&15)*4;
          float4 f = *(const float4*)(qk + ((size_t)(b*256 + ct*32 + row))*1024 + h*64 + c0);
          *(float4*)&Qs[row][c0] = f;
        }
      }
      for (int i=tid; i<2048; i+=256){    // K half-tile 256x32
        int e = i>>3, c0 = (i&7)*4;
        float4 f = *(const float4*)(qk + ((size_t)(b*256 + e))*1024 + 512 + h*64 + dh*32 + c0);
        *(float4*)&Ks[e][c0] = f;
      }
      __syncthreads();
      #pragma unroll
      for (int dc=0; dc<8; ++dc){
        float4 q4[4], k4[8];
        #pragma unroll
        for (int r=0;r<4;r++) q4[r] = *(float4*)&Qs[ty*4+r][dh*32+dc*4];
        #pragma unroll
        for (int j=0;j<8;j++) k4[j] = *(float4*)&Ks[j*32+tx][dc*4];
        #pragma unroll
        for (int r=0;r<4;r++)
          #pragma unroll
          for (int j=0;j<8;j++)
            sreg[r][j] += q4[r].x*k4[j].x + q4[r].y*k4[j].y
                        + q4[r].z*k4[j].z + q4[r].w*k4[j].w;
      }
    }
    // softmax over e (8 regs x 32 lanes), accumulate
    #pragma unroll
    for (int r=0;r<4;r++){
      float mx = -3.0e38f;
      #pragma unroll
      for (int j=0;j<8;j++){ sreg[r][j] *= 0.125f; mx = fmaxf(mx, sreg[r][j]); }
      #pragma unroll
      for (int off=1; off<32; off<<=1) mx = fmaxf(mx, __shfl_xor(mx, off, 32));
      float s = 0.0f;
      #pragma unroll
      for (int j=0;j<8;j++){ float p = __expf(sreg[r][j]-mx); sreg[r][j]=p; s += p; }
      #pragma unroll
      for (int off=1; off<32; off<<=1) s += __shfl_xor(s, off, 32);
      float inv = 1.0f/s;
      #pragma unroll
      for (int j=0;j<8;j++) fRes[r][j] += sreg[r][j]*inv;
    }
  }
  float* P = Pout + (size_t)hg*1048576;
  #pragma unroll
  for (int r=0;r<4;r++){
    size_t rowb = ((size_t)b*256 + ct*32 + ty*4 + r)*256;
    #pragma unroll
    for (int j=0;j<8;j++)
      P[rowb + j*32 + tx] = fRes[r][j];
  }
}

// Combine head-group partials: sw = (P0+P1)/8 -> fp32 out1, bf16 swB.
__global__ void spatial_combine(const float* __restrict__ P,
                                float* __restrict__ out1, bf16* __restrict__ swB){
  size_t i = (size_t)blockIdx.x*256 + threadIdx.x;
  float v = (P[i] + P[i + 1048576]) * 0.125f;
  out1[i] = v;
  swB[i]  = __float2bfloat16(v);
}

extern "C" void kernel_launch(void* const* d_in, const int* in_sizes, int n_in,
                              void* d_out, int out_size, void* d_ws, size_t ws_size,
                              hipStream_t stream){
  (void)in_sizes; (void)n_in; (void)out_size; (void)ws_size;
  const float* x_T  = (const float*)d_in[0];
  const float* x_S  = (const float*)d_in[1];
  const float* Wq_t = (const float*)d_in[2];
  const float* Wk_t = (const float*)d_in[3];
  const float* Wv_t = (const float*)d_in[4];
  const float* Wo   = (const float*)d_in[5];
  const float* Wq_s = (const float*)d_in[6];
  const float* Wk_s = (const float*)d_in[7];
  const float* f1w1 = (const float*)d_in[8];
  const float* f1b1 = (const float*)d_in[9];
  const float* f1w2 = (const float*)d_in[10];
  const float* f1b2 = (const float*)d_in[11];
  const float* f2w1 = (const float*)d_in[12];
  const float* f2b1 = (const float*)d_in[13];
  const float* f2w2 = (const float*)d_in[14];
  const float* f2b2 = (const float*)d_in[15];
  const float* tl1w = (const float*)d_in[16];
  const float* tl1b = (const float*)d_in[17];
  const float* tl2w = (const float*)d_in[18];
  const float* tl2b = (const float*)d_in[19];
  const float* sl1w = (const float*)d_in[20];
  const float* sl1b = (const float*)d_in[21];
  const float* flw  = (const float*)d_in[22];
  const float* flb  = (const float*)d_in[23];

  float* ws = (float*)d_ws;
  size_t off = 0;
  float* WtS    = ws + off; off += (size_t)512*1024;      // fp32 spatial weights [T x 2*512]
  bf16*  Wqkvb  = (bf16*)(ws + off); off += 768*256/2;
  bf16*  Wob    = (bf16*)(ws + off); off += 256*256/2;
  bf16*  f1w1b  = (bf16*)(ws + off); off += 1024*256/2;
  bf16*  f1w2b  = (bf16*)(ws + off); off += 256*1024/2;
  bf16*  f2w1b  = (bf16*)(ws + off); off += 1024*256/2;
  bf16*  f2w2b  = (bf16*)(ws + off); off += 256*1024/2;
  bf16*  bufHb  = (bf16*)(ws + off); off += (size_t)8192*256/2;
  bf16*  bufBigB= (bf16*)(ws + off); off += (size_t)8192*1024/2;
  bf16*  bufOb  = (bf16*)(ws + off); off += (size_t)8192*256/2;
  bf16*  bufTOb = (bf16*)(ws + off); off += (size_t)8192*256/2;
  bf16*  swB    = (bf16*)(ws + off); off += (size_t)16*256*256/2;
  float* bufH   = ws + off; off += (size_t)4096*512;      // spatial LN out (fp32)
  float* bufBig = ws + off; off += (size_t)8192*768;      // qkv fp32 / spatial qk fp32
  float* bufX   = ws + off; off += (size_t)8192*256;
  float* bufTO  = ws + off; off += (size_t)8192*256;
  float* bufX2  = ws + off; off += (size_t)8192*256;
  float* Pbuf   = ws + off; off += (size_t)2*16*256*256;  // two head-group partials

  float* out0 = (float*)d_out;                      // [B,T,C]
  float* out1 = out0 + (size_t)16*512*256;          // spatial_weights [B,C,C]

  // ---- weight prep ----
  to_bf16<<<256 ,256,0,stream>>>(Wqkvb,          Wq_t, 65536);
  to_bf16<<<256 ,256,0,stream>>>(Wqkvb+65536,    Wk_t, 65536);
  to_bf16<<<256 ,256,0,stream>>>(Wqkvb+131072,   Wv_t, 65536);
  to_bf16<<<256 ,256,0,stream>>>(Wob,            Wo,   65536);
  to_bf16<<<1024,256,0,stream>>>(f1w1b,          f1w1, 262144);
  to_bf16<<<1024,256,0,stream>>>(f1w2b,          f1w2, 262144);
  to_bf16<<<1024,256,0,stream>>>(f2w1b,          f2w1, 262144);
  to_bf16<<<1024,256,0,stream>>>(f2w2b,          f2w2, 262144);
  transpose_w<<<1024,256,0,stream>>>(WtS, Wq_s, 512, 512, 1024, 0  );
  transpose_w<<<1024,256,0,stream>>>(WtS, Wk_s, 512, 512, 1024, 512);

  // 1. h = LN(x_T) -> bf16
  ln_kernel<bf16><<<8192,256,0,stream>>>(bufHb, x_T, tl1w, tl1b, 256);
  // 2. qkv = h @ [Wq|Wk|Wv]^T (MFMA) -> fp32 for flash
  gemm_mfma<<<dim3(64,12,1),128,0,stream>>>(bufHb, Wqkvb, bufBig, nullptr,
        nullptr, nullptr, 8192,768,256, 0, 0,0,0,0);
  // 3. temporal causal attention (flash) -> bf16 o
  flash_tattn<<<dim3(8,8,16),256,0,stream>>>(bufBig, bufOb);
  // 4. x = o @ Wo^T + x_T (MFMA)
  gemm_mfma<<<dim3(64,4,1),128,0,stream>>>(bufOb, Wob, bufX, nullptr,
        nullptr, x_T, 8192,256,256, F_RES, 0,0,0,0);
  // 5. h2 = LN(x) -> bf16
  ln_kernel<bf16><<<8192,256,0,stream>>>(bufHb, bufX, tl2w, tl2b, 256);
  // 6. f1 = relu(h2 @ w1^T + b1) (MFMA) -> bf16
  gemm_mfma<<<dim3(64,16,1),128,0,stream>>>(bufHb, f1w1b, nullptr, bufBigB,
        f1b1, nullptr, 8192,1024,256, F_BIAS|F_RELU, 0,0,0,0);
  // 7. temporal_out = f1 @ w2^T + b2 + x (MFMA) -> fp32 + bf16
  gemm_mfma<<<dim3(64,4,1),128,0,stream>>>(bufBigB, f1w2b, bufTO, bufTOb,
        f1b2, bufX, 8192,256,1024, F_BIAS|F_RES, 0,0,0,0);
  // 8. hs = LN(x_S) over T -> fp32 (spatial path stays fp32)
  ln_kernel<float><<<4096,256,0,stream>>>(bufH, x_S, sl1w, sl1b, 512);
  // 9. [qs|ks] = hs @ [Wq_s|Wk_s]^T (fp32)
  gemm_k<<<dim3(64,16,1),256,0,stream>>>(bufH, WtS, bufBig,
        nullptr, nullptr, 4096,1024,512, 0);
  // 10. spatial softmax partials (two 4-head groups)
  spatial_attn2<<<dim3(8,16,2),256,0,stream>>>(bufBig, Pbuf);
  // 10b. combine -> out1 fp32 + swB bf16
  spatial_combine<<<4096,256,0,stream>>>(Pbuf, out1, swB);
  // 11. x2 = TO @ sw[b]^T + TO  (MFMA, batched; B operand = sw[b][c][e] native [N][K])
  gemm_mfma<<<dim3(4,4,16),128,0,stream>>>(bufTOb, swB, bufX2, nullptr,
        nullptr, bufTO, 512,256,256, F_RES, 131072, 65536, 131072, 131072);
  // 12. h3 = LN(x2) -> bf16
  ln_kernel<bf16><<<8192,256,0,stream>>>(bufHb, bufX2, flw, flb, 256);
  // 13. f2 hidden (MFMA) -> bf16
  gemm_mfma<<<dim3(64,16,1),128,0,stream>>>(bufHb, f2w1b, nullptr, bufBigB,
        f2b1, nullptr, 8192,1024,256, F_BIAS|F_RELU, 0,0,0,0);
  // 14. out = f2 @ w2^T + b2 + x2 (MFMA) -> fp32 d_out
  gemm_mfma<<<dim3(64,4,1),128,0,stream>>>(bufBigB, f2w2b, out0, nullptr,
        f2b2, bufX2, 8192,256,1024, F_BIAS|F_RES, 0,0,0,0);
}

// Round 6
// 445.755 us; speedup vs baseline: 3.6709x; 1.2781x over previous
//
#include <hip/hip_runtime.h>
#include <hip/hip_bf16.h>

typedef __hip_bfloat16 bf16;
typedef __attribute__((ext_vector_type(8))) short short8;
typedef __attribute__((ext_vector_type(4))) float f32x4;

#define F_BIAS 1
#define F_RELU 2
#define F_RES  4

__device__ __forceinline__ void st_out(float* p, float v){ *p = v; }
__device__ __forceinline__ void st_out(bf16* p, float v){ *p = __float2bfloat16(v); }

// fp32 -> bf16 elementwise
__global__ void to_bf16(bf16* __restrict__ dst, const float* __restrict__ src, int n){
  int i = blockIdx.x*256 + threadIdx.x;
  if (i < n) dst[i] = __float2bfloat16(src[i]);
}

// Row LayerNorm: one block per row, 256 threads, rowLen in {256, 512}.
template <typename OutT>
__global__ __launch_bounds__(256) void ln_kernel(OutT* __restrict__ dst,
    const float* __restrict__ src, const float* __restrict__ w,
    const float* __restrict__ bvec, int rowLen){
  int row = blockIdx.x, tid = threadIdx.x;
  const float* s = src + (size_t)row*rowLen;
  float x0 = s[tid];
  float x1 = (rowLen > 256) ? s[tid+256] : 0.0f;
  float sum = x0 + x1, sq = x0*x0 + x1*x1;
  #pragma unroll
  for (int off=32; off; off>>=1){
    sum += __shfl_down(sum, off, 64);
    sq  += __shfl_down(sq , off, 64);
  }
  __shared__ float sbs[4], sbq[4];
  int wid = tid>>6, lane = tid&63;
  if (lane==0){ sbs[wid]=sum; sbq[wid]=sq; }
  __syncthreads();
  if (tid==0){
    float a=0, b2=0;
    for (int i=0;i<4;i++){ a+=sbs[i]; b2+=sbq[i]; }
    sbs[0]=a; sbq[0]=b2;
  }
  __syncthreads();
  float inv  = 1.0f/(float)rowLen;
  float mean = sbs[0]*inv;
  float var  = sbq[0]*inv - mean*mean;
  float rstd = rsqrtf(var + 1e-6f);
  OutT* d = dst + (size_t)row*rowLen;
  st_out(&d[tid], (x0-mean)*rstd*w[tid] + bvec[tid]);
  if (rowLen > 256)
    st_out(&d[tid+256], (x1-mean)*rstd*w[tid+256] + bvec[tid+256]);
}

// ---------------- MFMA bf16 GEMM ----------------
// C[M,N] = A[M,K](bf16) @ B[N,K](bf16)^T  (+bias fp32)(relu)(+resid fp32)
// Tile: M=128 x N=64, 128 threads = 2 waves, each wave a 64x64 subtile via
// 4x4 grid of mfma_f32_16x16x32_bf16.
// A/B frag lane: [idx=lane&15][k=quad*8+j]; C/D: col=lane&15, row=quad*4+reg.
// Requires M%128==0, N%64==0, K%32==0.
__global__ __launch_bounds__(128) void gemm_mfma(
    const bf16* __restrict__ A, const bf16* __restrict__ B,
    float* __restrict__ outF, bf16* __restrict__ outB,
    const float* __restrict__ bias, const float* __restrict__ resid,
    int M, int N, int K, int flags,
    long long sA, long long sB, long long sO, long long sR){
  int bz = blockIdx.z;
  A += (size_t)bz*sA;
  B += (size_t)bz*sB;
  __shared__ short As[128*32];
  __shared__ short Bs[64*32];
  int tid = threadIdx.x;
  int m0 = blockIdx.x*128, n0 = blockIdx.y*64;
  int w = tid >> 6, lane = tid & 63;
  int quad = lane >> 4, l16 = lane & 15;
  f32x4 acc[4][4];
  #pragma unroll
  for (int r=0;r<4;r++)
    #pragma unroll
    for (int j=0;j<4;j++)
      acc[r][j] = (f32x4){0.f,0.f,0.f,0.f};

  for (int k0 = 0; k0 < K; k0 += 32){
    #pragma unroll
    for (int c=0;c<4;c++){            // A tile: 128x32 bf16
      int i = tid + c*128;
      int row = i >> 2, c0 = (i & 3)*8;
      *(short8*)&As[row*32 + c0] =
        *(const short8*)(A + (size_t)(m0+row)*K + k0 + c0);
    }
    #pragma unroll
    for (int c=0;c<2;c++){            // B tile: 64x32 bf16
      int i = tid + c*128;
      int row = i >> 2, c0 = (i & 3)*8;
      *(short8*)&Bs[row*32 + c0] =
        *(const short8*)(B + (size_t)(n0+row)*K + k0 + c0);
    }
    __syncthreads();
    short8 af[4], bfr[4];
    #pragma unroll
    for (int r=0;r<4;r++) af[r]  = *(short8*)&As[(w*64 + r*16 + l16)*32 + quad*8];
    #pragma unroll
    for (int j=0;j<4;j++) bfr[j] = *(short8*)&Bs[(j*16 + l16)*32 + quad*8];
    #pragma unroll
    for (int r=0;r<4;r++)
      #pragma unroll
      for (int j=0;j<4;j++)
        acc[r][j] = __builtin_amdgcn_mfma_f32_16x16x32_bf16(af[r], bfr[j], acc[r][j], 0,0,0);
    __syncthreads();
  }
  #pragma unroll
  for (int r=0;r<4;r++){
    int mb = m0 + w*64 + r*16 + quad*4;
    #pragma unroll
    for (int j=0;j<4;j++){
      int n = n0 + j*16 + l16;
      float bv = (flags & F_BIAS) ? bias[n] : 0.0f;
      #pragma unroll
      for (int e=0;e<4;e++){
        float v = acc[r][j][e] + bv;
        if (flags & F_RELU) v = fmaxf(v, 0.0f);
        size_t idx = (size_t)(mb+e)*N + n;
        if (flags & F_RES) v += resid[(size_t)bz*sR + idx];
        if (outF) outF[(size_t)bz*sO + idx] = v;
        if (outB) st_out(outB + (size_t)bz*sO + idx, v);
      }
    }
  }
}

// ---------------- MFMA flash temporal causal attention ----------------
// qkv bf16: row = b*512+t (stride 768), [0:256)=q, [256:512)=k, [512:768)=v,
// col = h*32+d. One block per (qt=64 queries, h, b); 4 waves, wave w owns
// Q rows w*16..+15. QK^T: A=Q[16x32] native, B=K[16x32] native (4 col tiles).
// Online softmax in C/D layout (row=quad*4+e). P -> LDS bf16 -> A-frag for PV;
// V transposed in LDS (Vt[d][s] = B[n=d][k=s]).
__global__ __launch_bounds__(256) void flash_mfma(
    const bf16* __restrict__ qkv, bf16* __restrict__ o){
  int qt = blockIdx.x, h = blockIdx.y, b = blockIdx.z;
  int tid = threadIdx.x;
  int w = tid>>6, lane = tid&63, quad = lane>>4, l16 = lane&15;
  __shared__ bf16 Qs[64*40];   // stride 40 (80 B, 16B-aligned rows)
  __shared__ bf16 Ks[64*40];
  __shared__ bf16 Vt[32*72];   // [d][s], stride 72
  __shared__ bf16 Ps[64*72];   // [row][s], wave-partitioned rows
  const bf16* base = qkv + (size_t)b*512*768;
  int t0 = qt*64;
  {
    int row = tid>>2, c0 = (tid&3)*8;
    *(short8*)&Qs[row*40+c0] =
      *(const short8*)(base + (size_t)(t0+row)*768 + h*32 + c0);
  }
  f32x4 accO[2];
  accO[0] = (f32x4){0.f,0.f,0.f,0.f};
  accO[1] = (f32x4){0.f,0.f,0.f,0.f};
  float m_i[4], l_i[4];
  #pragma unroll
  for (int e=0;e<4;e++){ m_i[e] = -3.0e38f; l_i[e] = 0.0f; }
  const float scale = 0.17677669529663687f; // 1/sqrt(32)

  for (int kt = 0; kt <= qt; ++kt){
    int s0 = kt*64;
    __syncthreads();                       // prev-iter readers done / Q staged
    {
      int row = tid>>2, c0 = (tid&3)*8;
      const bf16* rp = base + (size_t)(s0+row)*768 + h*32 + c0;
      *(short8*)&Ks[row*40+c0] = *(const short8*)(rp + 256);
      short8 v = *(const short8*)(rp + 512);
      #pragma unroll
      for (int q=0;q<8;q++){
        short tmp = v[q];
        Vt[(c0+q)*72 + row] = *(bf16*)&tmp;
      }
    }
    __syncthreads();
    // S = Q K^T for this wave's 16 rows
    short8 aq = *(short8*)&Qs[(w*16+l16)*40 + quad*8];
    f32x4 S[4];
    #pragma unroll
    for (int j2=0;j2<4;j2++){
      short8 bk = *(short8*)&Ks[(j2*16+l16)*40 + quad*8];
      S[j2] = __builtin_amdgcn_mfma_f32_16x16x32_bf16(aq, bk,
                (f32x4){0.f,0.f,0.f,0.f}, 0,0,0);
    }
    bool diag = (kt == qt);
    int qrow_base = t0 + w*16 + quad*4;
    #pragma unroll
    for (int e=0;e<4;e++){
      float sv[4];
      #pragma unroll
      for (int j2=0;j2<4;j2++){
        float x = S[j2][e]*scale;
        if (diag && (s0 + j2*16 + l16 > qrow_base + e)) x = -3.0e38f;
        sv[j2] = x;
      }
      float mx = fmaxf(fmaxf(sv[0],sv[1]), fmaxf(sv[2],sv[3]));
      #pragma unroll
      for (int off=1; off<16; off<<=1) mx = fmaxf(mx, __shfl_xor(mx, off, 64));
      float m_new = fmaxf(m_i[e], mx);
      float alpha = __expf(m_i[e]-m_new);
      float rs = 0.0f;
      #pragma unroll
      for (int j2=0;j2<4;j2++){
        float p = __expf(sv[j2]-m_new);
        rs += p;
        Ps[(w*16+quad*4+e)*72 + j2*16 + l16] = __float2bfloat16(p);
      }
      #pragma unroll
      for (int off=1; off<16; off<<=1) rs += __shfl_xor(rs, off, 64);
      l_i[e] = l_i[e]*alpha + rs;
      m_i[e] = m_new;
      accO[0][e] *= alpha;
      accO[1][e] *= alpha;
    }
    __syncthreads();                        // Ps visible
    #pragma unroll
    for (int sh=0; sh<2; ++sh){
      short8 ap = *(short8*)&Ps[(w*16+l16)*72 + sh*32 + quad*8];
      #pragma unroll
      for (int dh=0; dh<2; ++dh){
        short8 bv = *(short8*)&Vt[(dh*16+l16)*72 + sh*32 + quad*8];
        accO[dh] = __builtin_amdgcn_mfma_f32_16x16x32_bf16(ap, bv, accO[dh], 0,0,0);
      }
    }
  }
  #pragma unroll
  for (int e=0;e<4;e++){
    float inv = 1.0f/l_i[e];
    int t = t0 + w*16 + quad*4 + e;
    bf16* op = o + ((size_t)(b*512+t))*256 + h*32 + l16;
    op[0]  = __float2bfloat16(accO[0][e]*inv);
    op[16] = __float2bfloat16(accO[1][e]*inv);
  }
}

// Tiled spatial attention, partial over a 4-head group.
// qk fp32: row = b*256+c (stride 1024), cols [0:512)=qs (h*64+d), [512:1024)=ks.
// grid (ct=8, b=16, hg=2), 256 threads.
__global__ __launch_bounds__(256) void spatial_attn2(
    const float* __restrict__ qk, float* __restrict__ Pout){
  int ct = blockIdx.x, b = blockIdx.y, hg = blockIdx.z;
  int tid = threadIdx.x;
  int tx = tid & 31, ty = tid >> 5;
  __shared__ float Qs[32][64];
  __shared__ float Ks[256][36];
  float fRes[4][8];
  #pragma unroll
  for (int r=0;r<4;r++)
    #pragma unroll
    for (int j=0;j<8;j++) fRes[r][j] = 0.0f;

  for (int hh=0; hh<4; ++hh){
    int h = hg*4 + hh;
    float sreg[4][8];
    #pragma unroll
    for (int r=0;r<4;r++)
      #pragma unroll
      for (int j=0;j<8;j++) sreg[r][j] = 0.0f;
    for (int dh=0; dh<2; ++dh){
      __syncthreads();
      if (dh==0){
        for (int i=tid; i<512; i+=256){   // Q tile 32x64
          int row = i>>4, c0 = (i&15)*4;
          float4 f = *(const float4*)(qk + ((size_t)(b*256 + ct*32 + row))*1024 + h*64 + c0);
          *(float4*)&Qs[row][c0] = f;
        }
      }
      for (int i=tid; i<2048; i+=256){    // K half-tile 256x32
        int e = i>>3, c0 = (i&7)*4;
        float4 f = *(const float4*)(qk + ((size_t)(b*256 + e))*1024 + 512 + h*64 + dh*32 + c0);
        *(float4*)&Ks[e][c0] = f;
      }
      __syncthreads();
      #pragma unroll
      for (int dc=0; dc<8; ++dc){
        float4 q4[4], k4[8];
        #pragma unroll
        for (int r=0;r<4;r++) q4[r] = *(float4*)&Qs[ty*4+r][dh*32+dc*4];
        #pragma unroll
        for (int j=0;j<8;j++) k4[j] = *(float4*)&Ks[j*32+tx][dc*4];
        #pragma unroll
        for (int r=0;r<4;r++)
          #pragma unroll
          for (int j=0;j<8;j++)
            sreg[r][j] += q4[r].x*k4[j].x + q4[r].y*k4[j].y
                        + q4[r].z*k4[j].z + q4[r].w*k4[j].w;
      }
    }
    #pragma unroll
    for (int r=0;r<4;r++){
      float mx = -3.0e38f;
      #pragma unroll
      for (int j=0;j<8;j++){ sreg[r][j] *= 0.125f; mx = fmaxf(mx, sreg[r][j]); }
      #pragma unroll
      for (int off=1; off<32; off<<=1) mx = fmaxf(mx, __shfl_xor(mx, off, 32));
      float s = 0.0f;
      #pragma unroll
      for (int j=0;j<8;j++){ float p = __expf(sreg[r][j]-mx); sreg[r][j]=p; s += p; }
      #pragma unroll
      for (int off=1; off<32; off<<=1) s += __shfl_xor(s, off, 32);
      float inv = 1.0f/s;
      #pragma unroll
      for (int j=0;j<8;j++) fRes[r][j] += sreg[r][j]*inv;
    }
  }
  float* P = Pout + (size_t)hg*1048576;
  #pragma unroll
  for (int r=0;r<4;r++){
    size_t rowb = ((size_t)b*256 + ct*32 + ty*4 + r)*256;
    #pragma unroll
    for (int j=0;j<8;j++)
      P[rowb + j*32 + tx] = fRes[r][j];
  }
}

// Combine head-group partials: sw = (P0+P1)/8 -> fp32 out1, bf16 swB.
__global__ void spatial_combine(const float* __restrict__ P,
                                float* __restrict__ out1, bf16* __restrict__ swB){
  size_t i = (size_t)blockIdx.x*256 + threadIdx.x;
  float v = (P[i] + P[i + 1048576]) * 0.125f;
  out1[i] = v;
  swB[i]  = __float2bfloat16(v);
}

extern "C" void kernel_launch(void* const* d_in, const int* in_sizes, int n_in,
                              void* d_out, int out_size, void* d_ws, size_t ws_size,
                              hipStream_t stream){
  (void)in_sizes; (void)n_in; (void)out_size; (void)ws_size;
  const float* x_T  = (const float*)d_in[0];
  const float* x_S  = (const float*)d_in[1];
  const float* Wq_t = (const float*)d_in[2];
  const float* Wk_t = (const float*)d_in[3];
  const float* Wv_t = (const float*)d_in[4];
  const float* Wo   = (const float*)d_in[5];
  const float* Wq_s = (const float*)d_in[6];
  const float* Wk_s = (const float*)d_in[7];
  const float* f1w1 = (const float*)d_in[8];
  const float* f1b1 = (const float*)d_in[9];
  const float* f1w2 = (const float*)d_in[10];
  const float* f1b2 = (const float*)d_in[11];
  const float* f2w1 = (const float*)d_in[12];
  const float* f2b1 = (const float*)d_in[13];
  const float* f2w2 = (const float*)d_in[14];
  const float* f2b2 = (const float*)d_in[15];
  const float* tl1w = (const float*)d_in[16];
  const float* tl1b = (const float*)d_in[17];
  const float* tl2w = (const float*)d_in[18];
  const float* tl2b = (const float*)d_in[19];
  const float* sl1w = (const float*)d_in[20];
  const float* sl1b = (const float*)d_in[21];
  const float* flw  = (const float*)d_in[22];
  const float* flb  = (const float*)d_in[23];

  float* ws = (float*)d_ws;
  size_t off = 0;
  bf16*  Wqkvb  = (bf16*)(ws + off); off += 768*256/2;
  bf16*  Wob    = (bf16*)(ws + off); off += 256*256/2;
  bf16*  f1w1b  = (bf16*)(ws + off); off += 1024*256/2;
  bf16*  f1w2b  = (bf16*)(ws + off); off += 256*1024/2;
  bf16*  f2w1b  = (bf16*)(ws + off); off += 1024*256/2;
  bf16*  f2w2b  = (bf16*)(ws + off); off += 256*1024/2;
  bf16*  WSb    = (bf16*)(ws + off); off += 1024*512/2;
  bf16*  bufHb  = (bf16*)(ws + off); off += (size_t)8192*256/2;   // also 4096x512
  bf16*  bufQKVb= (bf16*)(ws + off); off += (size_t)8192*768/2;
  bf16*  bufBigB= (bf16*)(ws + off); off += (size_t)8192*1024/2;
  bf16*  bufOb  = (bf16*)(ws + off); off += (size_t)8192*256/2;
  bf16*  bufTOb = (bf16*)(ws + off); off += (size_t)8192*256/2;
  bf16*  swB    = (bf16*)(ws + off); off += (size_t)16*256*256/2;
  float* bufBig = ws + off; off += (size_t)4096*1024;   // spatial qk fp32
  float* bufX   = ws + off; off += (size_t)8192*256;
  float* bufTO  = ws + off; off += (size_t)8192*256;
  float* bufX2  = ws + off; off += (size_t)8192*256;
  float* Pbuf   = ws + off; off += (size_t)2*16*256*256;

  float* out0 = (float*)d_out;                      // [B,T,C]
  float* out1 = out0 + (size_t)16*512*256;          // spatial_weights [B,C,C]

  // ---- weight prep (fp32 -> bf16; all consumed natively as [N][K]) ----
  to_bf16<<<256 ,256,0,stream>>>(Wqkvb,          Wq_t, 65536);
  to_bf16<<<256 ,256,0,stream>>>(Wqkvb+65536,    Wk_t, 65536);
  to_bf16<<<256 ,256,0,stream>>>(Wqkvb+131072,   Wv_t, 65536);
  to_bf16<<<256 ,256,0,stream>>>(Wob,            Wo,   65536);
  to_bf16<<<1024,256,0,stream>>>(f1w1b,          f1w1, 262144);
  to_bf16<<<1024,256,0,stream>>>(f1w2b,          f1w2, 262144);
  to_bf16<<<1024,256,0,stream>>>(f2w1b,          f2w1, 262144);
  to_bf16<<<1024,256,0,stream>>>(f2w2b,          f2w2, 262144);
  to_bf16<<<1024,256,0,stream>>>(WSb,            Wq_s, 262144);
  to_bf16<<<1024,256,0,stream>>>(WSb+262144,     Wk_s, 262144);

  // 1. h = LN(x_T) -> bf16
  ln_kernel<bf16><<<8192,256,0,stream>>>(bufHb, x_T, tl1w, tl1b, 256);
  // 2. qkv = h @ [Wq|Wk|Wv]^T (MFMA) -> bf16
  gemm_mfma<<<dim3(64,12,1),128,0,stream>>>(bufHb, Wqkvb, nullptr, bufQKVb,
        nullptr, nullptr, 8192,768,256, 0, 0,0,0,0);
  // 3. temporal causal attention (MFMA flash) -> bf16 o
  flash_mfma<<<dim3(8,8,16),256,0,stream>>>(bufQKVb, bufOb);
  // 4. x = o @ Wo^T + x_T (MFMA)
  gemm_mfma<<<dim3(64,4,1),128,0,stream>>>(bufOb, Wob, bufX, nullptr,
        nullptr, x_T, 8192,256,256, F_RES, 0,0,0,0);
  // 5. h2 = LN(x) -> bf16
  ln_kernel<bf16><<<8192,256,0,stream>>>(bufHb, bufX, tl2w, tl2b, 256);
  // 6. f1 = relu(h2 @ w1^T + b1) (MFMA) -> bf16
  gemm_mfma<<<dim3(64,16,1),128,0,stream>>>(bufHb, f1w1b, nullptr, bufBigB,
        f1b1, nullptr, 8192,1024,256, F_BIAS|F_RELU, 0,0,0,0);
  // 7. temporal_out = f1 @ w2^T + b2 + x (MFMA) -> fp32 + bf16
  gemm_mfma<<<dim3(64,4,1),128,0,stream>>>(bufBigB, f1w2b, bufTO, bufTOb,
        f1b2, bufX, 8192,256,1024, F_BIAS|F_RES, 0,0,0,0);
  // 8. hs = LN(x_S) over T -> bf16
  ln_kernel<bf16><<<4096,256,0,stream>>>(bufHb, x_S, sl1w, sl1b, 512);
  // 9. [qs|ks] = hs @ [Wq_s|Wk_s]^T (MFMA) -> fp32 qk
  gemm_mfma<<<dim3(32,16,1),128,0,stream>>>(bufHb, WSb, bufBig, nullptr,
        nullptr, nullptr, 4096,1024,512, 0, 0,0,0,0);
  // 10. spatial softmax partials (two 4-head groups)
  spatial_attn2<<<dim3(8,16,2),256,0,stream>>>(bufBig, Pbuf);
  // 10b. combine -> out1 fp32 + swB bf16
  spatial_combine<<<4096,256,0,stream>>>(Pbuf, out1, swB);
  // 11. x2 = TO @ sw[b]^T + TO  (MFMA, batched; B operand = sw[b][c][e] native [N][K])
  gemm_mfma<<<dim3(4,4,16),128,0,stream>>>(bufTOb, swB, bufX2, nullptr,
        nullptr, bufTO, 512,256,256, F_RES, 131072, 65536, 131072, 131072);
  // 12. h3 = LN(x2) -> bf16
  ln_kernel<bf16><<<8192,256,0,stream>>>(bufHb, bufX2, flw, flb, 256);
  // 13. f2 hidden (MFMA) -> bf16
  gemm_mfma<<<dim3(64,16,1),128,0,stream>>>(bufHb, f2w1b, nullptr, bufBigB,
        f2b1, nullptr, 8192,1024,256, F_BIAS|F_RELU, 0,0,0,0);
  // 14. out = f2 @ w2^T + b2 + x2 (MFMA) -> fp32 d_out
  gemm_mfma<<<dim3(64,4,1),128,0,stream>>>(bufBigB, f2w2b, out0, nullptr,
        f2b2, bufX2, 8192,256,1024, F_BIAS|F_RES, 0,0,0,0);
}

// Round 7
// 340.972 us; speedup vs baseline: 4.7989x; 1.3073x over previous
//
#include <hip/hip_runtime.h>
#include <hip/hip_bf16.h>

typedef __hip_bfloat16 bf16;
typedef __attribute__((ext_vector_type(8))) short short8;
typedef __attribute__((ext_vector_type(4))) float f32x4;

#define F_BIAS 1
#define F_RELU 2
#define F_RES  4

__device__ __forceinline__ void st_out(float* p, float v){ *p = v; }
__device__ __forceinline__ void st_out(bf16* p, float v){ *p = __float2bfloat16(v); }
__device__ __forceinline__ short f2bs(float f){
  bf16 h = __float2bfloat16(f);
  return *reinterpret_cast<short*>(&h);
}

// ---- fused weight prep: 10 fp32->bf16 segments in one launch ----
struct PrepArgs {
  const float* src[10];
  bf16* dst[10];
};
__global__ __launch_bounds__(256) void prep_weights(PrepArgs a){
  // segment ends (elements); all multiples of 65536 -> wave-uniform segs
  int v = blockIdx.x*256 + threadIdx.x;     // vec4 index, grid covers exactly
  int e = v*4;
  int seg = (e>=65536)+(e>=131072)+(e>=196608)+(e>=262144)+(e>=524288)
          + (e>=786432)+(e>=1048576)+(e>=1310720)+(e>=1572864);
  const int starts[10] = {0,65536,131072,196608,262144,524288,786432,
                          1048576,1310720,1572864};
  int off = e - starts[seg];
  float4 f = *(const float4*)(a.src[seg] + off);
  short4 o;
  o.x = f2bs(f.x); o.y = f2bs(f.y); o.z = f2bs(f.z); o.w = f2bs(f.w);
  *(short4*)((short*)a.dst[seg] + off) = o;
}

// Row LayerNorm: one block per row, 256 threads, rowLen in {256, 512}.
template <typename OutT>
__global__ __launch_bounds__(256) void ln_kernel(OutT* __restrict__ dst,
    const float* __restrict__ src, const float* __restrict__ w,
    const float* __restrict__ bvec, int rowLen){
  int row = blockIdx.x, tid = threadIdx.x;
  const float* s = src + (size_t)row*rowLen;
  float x0 = s[tid];
  float x1 = (rowLen > 256) ? s[tid+256] : 0.0f;
  float sum = x0 + x1, sq = x0*x0 + x1*x1;
  #pragma unroll
  for (int off=32; off; off>>=1){
    sum += __shfl_down(sum, off, 64);
    sq  += __shfl_down(sq , off, 64);
  }
  __shared__ float sbs[4], sbq[4];
  int wid = tid>>6, lane = tid&63;
  if (lane==0){ sbs[wid]=sum; sbq[wid]=sq; }
  __syncthreads();
  if (tid==0){
    float a=0, b2=0;
    for (int i=0;i<4;i++){ a+=sbs[i]; b2+=sbq[i]; }
    sbs[0]=a; sbq[0]=b2;
  }
  __syncthreads();
  float inv  = 1.0f/(float)rowLen;
  float mean = sbs[0]*inv;
  float var  = sbq[0]*inv - mean*mean;
  float rstd = rsqrtf(var + 1e-6f);
  OutT* d = dst + (size_t)row*rowLen;
  st_out(&d[tid], (x0-mean)*rstd*w[tid] + bvec[tid]);
  if (rowLen > 256)
    st_out(&d[tid+256], (x1-mean)*rstd*w[tid+256] + bvec[tid+256]);
}

// ---------------- MFMA bf16 GEMM v2 ----------------
// C[M,N] = A[M,K] @ B[N,K]^T (+bias)(relu)(+resid). BN=128, BK=32.
// 256 threads = 4 waves (2x2). BM=128: wave tile 64x64; BM=64: wave 32x64.
// Composite batch: bz -> (bhi=bz/bdiv, blo=bz%bdiv) with separate strides
// (for the per-(b,h) spatial score GEMM). lda/ldb/ldc in elements.
template<int BM>
__global__ __launch_bounds__(256) void gemm_mfma(
    const bf16* __restrict__ A, const bf16* __restrict__ B,
    float* __restrict__ outF, bf16* __restrict__ outB,
    const float* __restrict__ bias, const float* __restrict__ resid,
    int M, int N, int K, int lda, int ldb, int ldc, int flags, int bdiv,
    long long sA, long long sA2, long long sB, long long sB2,
    long long sO, long long sO2, long long sR){
  int bz = blockIdx.z;
  int bhi = bz / bdiv, blo = bz - bhi*bdiv;
  A += (size_t)bhi*sA + (size_t)blo*sA2;
  B += (size_t)bhi*sB + (size_t)blo*sB2;
  long long obase = (long long)bhi*sO + (long long)blo*sO2;
  __shared__ short As[BM*32];
  __shared__ short Bs[128*32];
  int tid = threadIdx.x;
  int m0 = blockIdx.x*BM, n0 = blockIdx.y*128;
  int w = tid>>6, lane = tid&63, quad = lane>>4, l16 = lane&15;
  constexpr int WM = BM/2;     // 64 or 32
  constexpr int MF = WM/16;    // 4 or 2
  int wm = (w>>1)*WM, wn = (w&1)*64;
  f32x4 acc[MF][4];
  #pragma unroll
  for (int r=0;r<MF;r++)
    #pragma unroll
    for (int j=0;j<4;j++)
      acc[r][j] = (f32x4){0.f,0.f,0.f,0.f};

  for (int k0 = 0; k0 < K; k0 += 32){
    #pragma unroll
    for (int c=0;c<BM/64;c++){          // A tile: BM x 32
      int i = tid + c*256;
      int row = i >> 2, c0 = (i & 3)*8;
      *(short8*)&As[row*32 + c0] =
        *(const short8*)(A + (size_t)(m0+row)*lda + k0 + c0);
    }
    #pragma unroll
    for (int c=0;c<2;c++){              // B tile: 128 x 32
      int i = tid + c*256;
      int row = i >> 2, c0 = (i & 3)*8;
      *(short8*)&Bs[row*32 + c0] =
        *(const short8*)(B + (size_t)(n0+row)*ldb + k0 + c0);
    }
    __syncthreads();
    short8 af[MF], bfr[4];
    #pragma unroll
    for (int r=0;r<MF;r++) af[r]  = *(short8*)&As[(wm + r*16 + l16)*32 + quad*8];
    #pragma unroll
    for (int j=0;j<4;j++)  bfr[j] = *(short8*)&Bs[(wn + j*16 + l16)*32 + quad*8];
    #pragma unroll
    for (int r=0;r<MF;r++)
      #pragma unroll
      for (int j=0;j<4;j++)
        acc[r][j] = __builtin_amdgcn_mfma_f32_16x16x32_bf16(af[r], bfr[j], acc[r][j], 0,0,0);
    __syncthreads();
  }
  #pragma unroll
  for (int r=0;r<MF;r++){
    int mb = m0 + wm + r*16 + quad*4;
    #pragma unroll
    for (int j=0;j<4;j++){
      int n = n0 + wn + j*16 + l16;
      float bv = (flags & F_BIAS) ? bias[n] : 0.0f;
      #pragma unroll
      for (int e=0;e<4;e++){
        float v = acc[r][j][e] + bv;
        if (flags & F_RELU) v = fmaxf(v, 0.0f);
        long long idx = obase + (long long)(mb+e)*ldc + n;
        if (flags & F_RES) v += resid[(long long)bz*sR + (long long)(mb+e)*ldc + n];
        if (outF) outF[idx] = v;
        if (outB) st_out(outB + idx, v);
      }
    }
  }
}

// ---------------- MFMA flash temporal causal attention ----------------
// qkv bf16: row = b*512+t (stride 768), [0:256)=q, [256:512)=k, [512:768)=v.
__global__ __launch_bounds__(256) void flash_mfma(
    const bf16* __restrict__ qkv, bf16* __restrict__ o){
  int qt = blockIdx.x, h = blockIdx.y, b = blockIdx.z;
  int tid = threadIdx.x;
  int w = tid>>6, lane = tid&63, quad = lane>>4, l16 = lane&15;
  __shared__ bf16 Qs[64*40];
  __shared__ bf16 Ks[64*40];
  __shared__ bf16 Vt[32*72];
  __shared__ bf16 Ps[64*72];
  const bf16* base = qkv + (size_t)b*512*768;
  int t0 = qt*64;
  {
    int row = tid>>2, c0 = (tid&3)*8;
    *(short8*)&Qs[row*40+c0] =
      *(const short8*)(base + (size_t)(t0+row)*768 + h*32 + c0);
  }
  f32x4 accO[2];
  accO[0] = (f32x4){0.f,0.f,0.f,0.f};
  accO[1] = (f32x4){0.f,0.f,0.f,0.f};
  float m_i[4], l_i[4];
  #pragma unroll
  for (int e=0;e<4;e++){ m_i[e] = -3.0e38f; l_i[e] = 0.0f; }
  const float scale = 0.17677669529663687f;

  for (int kt = 0; kt <= qt; ++kt){
    int s0 = kt*64;
    __syncthreads();
    {
      int row = tid>>2, c0 = (tid&3)*8;
      const bf16* rp = base + (size_t)(s0+row)*768 + h*32 + c0;
      *(short8*)&Ks[row*40+c0] = *(const short8*)(rp + 256);
      short8 v = *(const short8*)(rp + 512);
      #pragma unroll
      for (int q=0;q<8;q++){
        short tmp = v[q];
        Vt[(c0+q)*72 + row] = *(bf16*)&tmp;
      }
    }
    __syncthreads();
    short8 aq = *(short8*)&Qs[(w*16+l16)*40 + quad*8];
    f32x4 S[4];
    #pragma unroll
    for (int j2=0;j2<4;j2++){
      short8 bk = *(short8*)&Ks[(j2*16+l16)*40 + quad*8];
      S[j2] = __builtin_amdgcn_mfma_f32_16x16x32_bf16(aq, bk,
                (f32x4){0.f,0.f,0.f,0.f}, 0,0,0);
    }
    bool diag = (kt == qt);
    int qrow_base = t0 + w*16 + quad*4;
    #pragma unroll
    for (int e=0;e<4;e++){
      float sv[4];
      #pragma unroll
      for (int j2=0;j2<4;j2++){
        float x = S[j2][e]*scale;
        if (diag && (s0 + j2*16 + l16 > qrow_base + e)) x = -3.0e38f;
        sv[j2] = x;
      }
      float mx = fmaxf(fmaxf(sv[0],sv[1]), fmaxf(sv[2],sv[3]));
      #pragma unroll
      for (int off=1; off<16; off<<=1) mx = fmaxf(mx, __shfl_xor(mx, off, 64));
      float m_new = fmaxf(m_i[e], mx);
      float alpha = __expf(m_i[e]-m_new);
      float rs = 0.0f;
      #pragma unroll
      for (int j2=0;j2<4;j2++){
        float p = __expf(sv[j2]-m_new);
        rs += p;
        Ps[(w*16+quad*4+e)*72 + j2*16 + l16] = __float2bfloat16(p);
      }
      #pragma unroll
      for (int off=1; off<16; off<<=1) rs += __shfl_xor(rs, off, 64);
      l_i[e] = l_i[e]*alpha + rs;
      m_i[e] = m_new;
      accO[0][e] *= alpha;
      accO[1][e] *= alpha;
    }
    __syncthreads();
    #pragma unroll
    for (int sh=0; sh<2; ++sh){
      short8 ap = *(short8*)&Ps[(w*16+l16)*72 + sh*32 + quad*8];
      #pragma unroll
      for (int dh=0; dh<2; ++dh){
        short8 bv = *(short8*)&Vt[(dh*16+l16)*72 + sh*32 + quad*8];
        accO[dh] = __builtin_amdgcn_mfma_f32_16x16x32_bf16(ap, bv, accO[dh], 0,0,0);
      }
    }
  }
  #pragma unroll
  for (int e=0;e<4;e++){
    float inv = 1.0f/l_i[e];
    int t = t0 + w*16 + quad*4 + e;
    bf16* op = o + ((size_t)(b*512+t))*256 + h*32 + l16;
    op[0]  = __float2bfloat16(accO[0][e]*inv);
    op[16] = __float2bfloat16(accO[1][e]*inv);
  }
}

// ---- spatial softmax + head-mean: one wave per c-row, sync-free ----
// S fp32 [(b*8+h)][c][e] (ldc=256). Writes out1 fp32 + swB bf16 [b][c][e].
__global__ __launch_bounds__(256) void spatial_softmax_mean(
    const float* __restrict__ S, float* __restrict__ out1,
    bf16* __restrict__ swB){
  int row  = blockIdx.x*4 + (threadIdx.x>>6);   // b*256+c in [0,4096)
  int lane = threadIdx.x & 63;
  int b = row >> 8, c = row & 255;
  const float* p = S + (size_t)b*524288 + (size_t)c*256 + lane*4;
  float acc[4] = {0.f,0.f,0.f,0.f};
  for (int h=0; h<8; ++h){
    float4 v = *(const float4*)(p + h*65536);
    float a0 = v.x*0.125f, a1 = v.y*0.125f, a2 = v.z*0.125f, a3 = v.w*0.125f;
    float mx = fmaxf(fmaxf(a0,a1), fmaxf(a2,a3));
    #pragma unroll
    for (int off=1; off<64; off<<=1) mx = fmaxf(mx, __shfl_xor(mx, off, 64));
    float e0 = __expf(a0-mx), e1 = __expf(a1-mx),
          e2 = __expf(a2-mx), e3 = __expf(a3-mx);
    float s = e0+e1+e2+e3;
    #pragma unroll
    for (int off=1; off<64; off<<=1) s += __shfl_xor(s, off, 64);
    float inv = 1.0f/s;
    acc[0] += e0*inv; acc[1] += e1*inv; acc[2] += e2*inv; acc[3] += e3*inv;
  }
  size_t ob = (size_t)row*256 + lane*4;
  float4 o;
  o.x = acc[0]*0.125f; o.y = acc[1]*0.125f;
  o.z = acc[2]*0.125f; o.w = acc[3]*0.125f;
  *(float4*)(out1 + ob) = o;
  short4 s4;
  s4.x = f2bs(o.x); s4.y = f2bs(o.y); s4.z = f2bs(o.z); s4.w = f2bs(o.w);
  *(short4*)((short*)swB + ob) = s4;
}

extern "C" void kernel_launch(void* const* d_in, const int* in_sizes, int n_in,
                              void* d_out, int out_size, void* d_ws, size_t ws_size,
                              hipStream_t stream){
  (void)in_sizes; (void)n_in; (void)out_size; (void)ws_size;
  const float* x_T  = (const float*)d_in[0];
  const float* x_S  = (const float*)d_in[1];
  const float* Wq_t = (const float*)d_in[2];
  const float* Wk_t = (const float*)d_in[3];
  const float* Wv_t = (const float*)d_in[4];
  const float* Wo   = (const float*)d_in[5];
  const float* Wq_s = (const float*)d_in[6];
  const float* Wk_s = (const float*)d_in[7];
  const float* f1w1 = (const float*)d_in[8];
  const float* f1b1 = (const float*)d_in[9];
  const float* f1w2 = (const float*)d_in[10];
  const float* f1b2 = (const float*)d_in[11];
  const float* f2w1 = (const float*)d_in[12];
  const float* f2b1 = (const float*)d_in[13];
  const float* f2w2 = (const float*)d_in[14];
  const float* f2b2 = (const float*)d_in[15];
  const float* tl1w = (const float*)d_in[16];
  const float* tl1b = (const float*)d_in[17];
  const float* tl2w = (const float*)d_in[18];
  const float* tl2b = (const float*)d_in[19];
  const float* sl1w = (const float*)d_in[20];
  const float* sl1b = (const float*)d_in[21];
  const float* flw  = (const float*)d_in[22];
  const float* flb  = (const float*)d_in[23];

  float* ws = (float*)d_ws;
  size_t off = 0;
  bf16*  Wqkvb  = (bf16*)(ws + off); off += 768*256/2;
  bf16*  Wob    = (bf16*)(ws + off); off += 256*256/2;
  bf16*  f1w1b  = (bf16*)(ws + off); off += 1024*256/2;
  bf16*  f1w2b  = (bf16*)(ws + off); off += 256*1024/2;
  bf16*  f2w1b  = (bf16*)(ws + off); off += 1024*256/2;
  bf16*  f2w2b  = (bf16*)(ws + off); off += 256*1024/2;
  bf16*  WSb    = (bf16*)(ws + off); off += 1024*512/2;
  bf16*  bufHb  = (bf16*)(ws + off); off += (size_t)8192*256/2;
  bf16*  bufQKVb= (bf16*)(ws + off); off += (size_t)8192*768/2;
  bf16*  bufBigB= (bf16*)(ws + off); off += (size_t)8192*1024/2;
  bf16*  bufOb  = (bf16*)(ws + off); off += (size_t)8192*256/2;
  bf16*  bufTOb = (bf16*)(ws + off); off += (size_t)8192*256/2;
  bf16*  swB    = (bf16*)(ws + off); off += (size_t)16*256*256/2;
  bf16*  qkB    = (bf16*)(ws + off); off += (size_t)4096*1024/2;
  float* bufX   = ws + off; off += (size_t)8192*256;
  float* bufTO  = ws + off; off += (size_t)8192*256;
  float* bufX2  = ws + off; off += (size_t)8192*256;
  float* Sbuf   = ws + off; off += (size_t)128*65536;   // [b*8+h][256][256] fp32

  float* out0 = (float*)d_out;                      // [B,T,C]
  float* out1 = out0 + (size_t)16*512*256;          // spatial_weights [B,C,C]

  // ---- fused weight prep (1 launch) ----
  PrepArgs pa;
  pa.src[0]=Wq_t;  pa.dst[0]=Wqkvb;
  pa.src[1]=Wk_t;  pa.dst[1]=Wqkvb+65536;
  pa.src[2]=Wv_t;  pa.dst[2]=Wqkvb+131072;
  pa.src[3]=Wo;    pa.dst[3]=Wob;
  pa.src[4]=f1w1;  pa.dst[4]=f1w1b;
  pa.src[5]=f1w2;  pa.dst[5]=f1w2b;
  pa.src[6]=f2w1;  pa.dst[6]=f2w1b;
  pa.src[7]=f2w2;  pa.dst[7]=f2w2b;
  pa.src[8]=Wq_s;  pa.dst[8]=WSb;
  pa.src[9]=Wk_s;  pa.dst[9]=WSb+262144;
  prep_weights<<<1792,256,0,stream>>>(pa);

  // 1. h = LN(x_T) -> bf16
  ln_kernel<bf16><<<8192,256,0,stream>>>(bufHb, x_T, tl1w, tl1b, 256);
  // 2. qkv (MFMA) -> bf16
  gemm_mfma<128><<<dim3(64,6,1),256,0,stream>>>(bufHb, Wqkvb, nullptr, bufQKVb,
        nullptr, nullptr, 8192,768,256, 256,256,768, 0, 1, 0,0,0,0,0,0,0);
  // 3. temporal causal flash attention -> bf16 o
  flash_mfma<<<dim3(8,8,16),256,0,stream>>>(bufQKVb, bufOb);
  // 4. x = o @ Wo^T + x_T
  gemm_mfma<64><<<dim3(128,2,1),256,0,stream>>>(bufOb, Wob, bufX, nullptr,
        nullptr, x_T, 8192,256,256, 256,256,256, F_RES, 1, 0,0,0,0,0,0,0);
  // 5. h2 = LN(x) -> bf16
  ln_kernel<bf16><<<8192,256,0,stream>>>(bufHb, bufX, tl2w, tl2b, 256);
  // 6. f1 = relu(h2 @ w1^T + b1) -> bf16
  gemm_mfma<128><<<dim3(64,8,1),256,0,stream>>>(bufHb, f1w1b, nullptr, bufBigB,
        f1b1, nullptr, 8192,1024,256, 256,256,1024, F_BIAS|F_RELU, 1, 0,0,0,0,0,0,0);
  // 7. temporal_out = f1 @ w2^T + b2 + x -> fp32 + bf16
  gemm_mfma<64><<<dim3(128,2,1),256,0,stream>>>(bufBigB, f1w2b, bufTO, bufTOb,
        f1b2, bufX, 8192,256,1024, 1024,1024,256, F_BIAS|F_RES, 1, 0,0,0,0,0,0,0);
  // 8. hs = LN(x_S) over T -> bf16
  ln_kernel<bf16><<<4096,256,0,stream>>>(bufHb, x_S, sl1w, sl1b, 512);
  // 9. [qs|ks] = hs @ [Wq_s|Wk_s]^T -> bf16 qkB
  gemm_mfma<128><<<dim3(32,8,1),256,0,stream>>>(bufHb, WSb, nullptr, qkB,
        nullptr, nullptr, 4096,1024,512, 512,512,1024, 0, 1, 0,0,0,0,0,0,0);
  // 10. spatial scores S[b,h] = Q @ K^T (batched MFMA, bdiv=8)
  gemm_mfma<128><<<dim3(2,2,128),256,0,stream>>>(qkB, qkB+512, Sbuf, nullptr,
        nullptr, nullptr, 256,256,64, 1024,1024,256, 0, 8,
        262144,64, 262144,64, 524288,65536, 0);
  // 10b. softmax over e + mean over h -> out1 fp32 + swB bf16
  spatial_softmax_mean<<<1024,256,0,stream>>>(Sbuf, out1, swB);
  // 11. x2 = TO @ sw[b]^T + TO (batched)
  gemm_mfma<64><<<dim3(8,2,16),256,0,stream>>>(bufTOb, swB, bufX2, nullptr,
        nullptr, bufTO, 512,256,256, 256,256,256, F_RES, 1,
        131072,0, 65536,0, 131072,0, 131072);
  // 12. h3 = LN(x2) -> bf16
  ln_kernel<bf16><<<8192,256,0,stream>>>(bufHb, bufX2, flw, flb, 256);
  // 13. f2 hidden -> bf16
  gemm_mfma<128><<<dim3(64,8,1),256,0,stream>>>(bufHb, f2w1b, nullptr, bufBigB,
        f2b1, nullptr, 8192,1024,256, 256,256,1024, F_BIAS|F_RELU, 1, 0,0,0,0,0,0,0);
  // 14. out = f2 @ w2^T + b2 + x2 -> fp32 d_out
  gemm_mfma<64><<<dim3(128,2,1),256,0,stream>>>(bufBigB, f2w2b, out0, nullptr,
        f2b2, bufX2, 8192,256,1024, 1024,1024,256, F_BIAS|F_RES, 1, 0,0,0,0,0,0,0);
}